// Round 17
// baseline (326.504 us; speedup 1.0000x reference)
//
#include <hip/hip_runtime.h>
#include <cstdint>
#include <cstddef>

#define NN 30000
#define NE 480000

typedef __attribute__((ext_vector_type(8))) short short8v;
typedef __attribute__((ext_vector_type(4))) float f32x4;

__device__ __forceinline__ float leakyf(float x){ return x > 0.f ? x : 0.2f * x; }
__device__ __forceinline__ float eluf(float x){ return x > 0.f ? x : expm1f(x); }

__device__ __forceinline__ float bf2f(unsigned short u){
  return __uint_as_float(((unsigned)u) << 16);
}
__device__ __forceinline__ unsigned short f2bf(float f){
  unsigned x = __float_as_uint(f);
  unsigned r = (x + 0x7FFFu + ((x >> 16) & 1u)) >> 16;
  return (unsigned short)r;
}

struct F4 { float x, y, z, w; };

__device__ __forceinline__ F4 ld4(const float* p){
  float4 v = *(const float4*)p;
  return F4{v.x, v.y, v.z, v.w};
}

__device__ __forceinline__ float4 redeg16(float4 v){
  v.x += __shfl_xor(v.x, 16); v.y += __shfl_xor(v.y, 16);
  v.z += __shfl_xor(v.z, 16); v.w += __shfl_xor(v.w, 16);
  v.x += __shfl_xor(v.x, 32); v.y += __shfl_xor(v.y, 32);
  v.z += __shfl_xor(v.z, 32); v.w += __shfl_xor(v.w, 32);
  return v;
}

// ---------------- CSR build ----------------

__global__ void zero2_kernel(int* __restrict__ a, int* __restrict__ b, int n){
  int i = blockIdx.x * blockDim.x + threadIdx.x;
  if (i < n){ a[i] = 0; b[i] = 0; }
}

__global__ void count_kernel(const int* __restrict__ dst, int* __restrict__ deg, int E){
  int i = blockIdx.x * blockDim.x + threadIdx.x;
  if (i < E) atomicAdd(&deg[dst[i]], 1);
}

__global__ void scan1_kernel(const int* __restrict__ deg, int* __restrict__ offs,
                             int* __restrict__ bsum){
  __shared__ int sh[256];
  int blk = blockIdx.x, t = threadIdx.x, i = blk * 256 + t;
  int v = (i < NN) ? deg[i] : 0;
  sh[t] = v; __syncthreads();
  for (int o = 1; o < 256; o <<= 1){
    int tv = (t >= o) ? sh[t - o] : 0;
    __syncthreads();
    sh[t] += tv;
    __syncthreads();
  }
  if (i < NN) offs[i + 1] = sh[t];
  if (t == 255) bsum[blk] = sh[255];
}

__global__ void scan2_kernel(int* __restrict__ bsum, int nb){
  __shared__ int sh[256];
  int t = threadIdx.x;
  int v = (t < nb) ? bsum[t] : 0;
  sh[t] = v; __syncthreads();
  for (int o = 1; o < 256; o <<= 1){
    int tv = (t >= o) ? sh[t - o] : 0;
    __syncthreads();
    sh[t] += tv;
    __syncthreads();
  }
  if (t < nb) bsum[t] = sh[t];
}

__global__ void scan3_kernel(const int* __restrict__ bsum, int* __restrict__ offs){
  int i = blockIdx.x * 256 + threadIdx.x;
  if (i == 0) offs[0] = 0;
  if (i < NN){
    int blk = i >> 8;
    int add = blk ? bsum[blk - 1] : 0;
    offs[i + 1] += add;
  }
}

__global__ void scatter_kernel(const int* __restrict__ src, const int* __restrict__ dst,
                               const int* __restrict__ et, const int* __restrict__ offs,
                               int* __restrict__ cursor, int* __restrict__ csr_src,
                               int* __restrict__ csr_et, int E){
  int i = blockIdx.x * blockDim.x + threadIdx.x;
  if (i < E){
    int d = dst[i];
    int pos = offs[d] + atomicAdd(&cursor[d], 1);
    csr_src[pos] = src[i];
    csr_et[pos]  = et[i];
  }
}

// ---------------- weight prep ----------------

// L3 B-fragments straight from basis2/root2 (virtual Wcat cols: 0..255 basis, 256..319 root).
// idx = (nf16*8 + ks)*64 + lane; element col = nf16*16+(lane&15), k = ks*32+(lane>>4)*8+j.
__global__ void packB2_kernel(const float* __restrict__ basis2, const float* __restrict__ root2,
                              unsigned short* __restrict__ Bhi, unsigned short* __restrict__ Blo){
  int idx = blockIdx.x * 256 + threadIdx.x;
  if (idx >= 10240) return;
  int lane = idx & 63;
  int rest = idx >> 6;
  int ks = rest & 7;
  int nf16 = rest >> 3;                       // 0..19
  int col = nf16 * 16 + (lane & 15);
  int kbase = ks * 32 + ((lane >> 4) << 3);
  size_t obase = (size_t)idx * 8;
  #pragma unroll
  for (int j = 0; j < 8; j++){
    int k = kbase + j;
    float v;
    if (col < 256){
      int b = col >> 6, c = col & 63;
      v = basis2[((size_t)b * 256 + k) * 64 + c];
    } else {
      v = root2[(size_t)k * 64 + (col - 256)];
    }
    unsigned short h = f2bf(v);
    float res = v - bf2f(h);
    Bhi[obase + j] = h;
    Blo[obase + j] = f2bf(res);
  }
}

// generic MFMA B-fragment pack (GAT1 Wg1), bf16 hi/lo split.
__global__ void packB_kernel(const float* __restrict__ W, int ldw, int ksteps, int total,
                             unsigned short* __restrict__ Bhi, unsigned short* __restrict__ Blo){
  int idx = blockIdx.x * 256 + threadIdx.x;
  if (idx >= total) return;
  int lane = idx & 63;
  int rest = idx >> 6;
  int ks = rest % ksteps;
  int nf16 = rest / ksteps;
  int col = nf16 * 16 + (lane & 15);
  int kbase = ks * 32 + ((lane >> 4) << 3);
  size_t obase = (size_t)idx * 8;
  #pragma unroll
  for (int j = 0; j < 8; j++){
    float v = W[(size_t)(kbase + j) * ldw + col];
    unsigned short h = f2bf(v);
    float res = v - bf2f(h);
    Bhi[obase + j] = h;
    Blo[obase + j] = f2bf(res);
  }
}

// wa_s[k*4+h] = sum_c Wg1[k, h*64+c] * atts1[h,c]  (and wa_d with attd1)
__global__ void wa_kernel(const float* __restrict__ Wg1, const float* __restrict__ atts1,
                          const float* __restrict__ attd1, float* __restrict__ wa_s,
                          float* __restrict__ wa_d){
  int t = threadIdx.x;
  int k = t >> 2, h = t & 3;
  float s = 0.f, d = 0.f;
  const float* wr = Wg1 + (size_t)k * 256 + h * 64;
  const float* pa = atts1 + h * 64;
  const float* pb = attd1 + h * 64;
  #pragma unroll 8
  for (int c = 0; c < 64; c++){ s += wr[c] * pa[c]; d += wr[c] * pb[c]; }
  wa_s[k * 4 + h] = s;
  wa_d[k * 4 + h] = d;
}

// ---------------- layer-1 basis-space aggregation (4 edge-groups x float2) ----------------

__global__ void agg1_kernel(const float* __restrict__ x, const float* __restrict__ comp,
                            const int* __restrict__ offs, const int* __restrict__ csr_src,
                            const int* __restrict__ csr_et, float* __restrict__ agg){
  int wid  = (blockIdx.x * blockDim.x + threadIdx.x) >> 6;
  int lane = threadIdx.x & 63;
  if (wid >= NN) return;
  int q = lane & 15, eg = lane >> 4;
  int c2 = q * 2;
  int n0 = offs[wid], n1 = offs[wid + 1];
  float a00 = 0.f, a01 = 0.f, a10 = 0.f, a11 = 0.f;
  float a20 = 0.f, a21 = 0.f, a30 = 0.f, a31 = 0.f;
  for (int k = n0 + eg; k < n1; k += 4){
    int s = csr_src[k], e = csr_et[k];
    float2 v = *(const float2*)(x + (size_t)s * 32 + c2);
    F4 cp = ld4(comp + (size_t)e * 4);
    a00 += cp.x * v.x; a01 += cp.x * v.y;
    a10 += cp.y * v.x; a11 += cp.y * v.y;
    a20 += cp.z * v.x; a21 += cp.z * v.y;
    a30 += cp.w * v.x; a31 += cp.w * v.y;
  }
  #pragma unroll
  for (int o = 16; o < 64; o <<= 1){
    a00 += __shfl_xor(a00, o); a01 += __shfl_xor(a01, o);
    a10 += __shfl_xor(a10, o); a11 += __shfl_xor(a11, o);
    a20 += __shfl_xor(a20, o); a21 += __shfl_xor(a21, o);
    a30 += __shfl_xor(a30, o); a31 += __shfl_xor(a31, o);
  }
  int dg = n1 - n0;
  float sc = 1.f / (float)(dg > 0 ? dg : 1);
  if (lane < 16){
    float* ar = agg + (size_t)wid * 128 + c2;
    *(float2*)(ar)      = make_float2(a00 * sc, a01 * sc);
    *(float2*)(ar + 32) = make_float2(a10 * sc, a11 * sc);
    *(float2*)(ar + 64) = make_float2(a20 * sc, a21 * sc);
    *(float2*)(ar + 96) = make_float2(a30 * sc, a31 * sc);
  }
}

// ---------------- (RPT*16)-row x 64-col fused GEMM (layer 1), logits fused ----------------

template<int RPT, bool ELU, bool LOGITS>
__global__ __launch_bounds__(256) void gemmT_kernel(
    const float* __restrict__ A1, int lda1, int K1,
    const float* __restrict__ W1, int ldw1,
    const float* __restrict__ A2, int lda2, int K2,
    const float* __restrict__ W2, int ldw2,
    const float* __restrict__ bias,
    float* __restrict__ Y, int ldy,
    int nrows,
    const float* __restrict__ wa_s, const float* __restrict__ wa_d,
    float* __restrict__ as_, float* __restrict__ ad_)
{
  __shared__ float At[32][RPT * 16 + 4];
  __shared__ float Wl[32][68];
  int t = threadIdx.x;
  int tc = t & 15, tr = t >> 4;
  int nbase = blockIdx.x * (RPT * 16);
  float acc[RPT][4];
  #pragma unroll
  for (int j = 0; j < RPT; j++)
    #pragma unroll
    for (int i = 0; i < 4; i++) acc[j][i] = 0.f;

  for (int seg = 0; seg < 2; seg++){
    const float* A = seg ? A2 : A1;
    const float* W = seg ? W2 : W1;
    int lda = seg ? lda2 : lda1;
    int ldw = seg ? ldw2 : ldw1;
    int K   = seg ? K2 : K1;
    if (A == nullptr || K <= 0) continue;
    for (int k0 = 0; k0 < K; k0 += 32){
      #pragma unroll
      for (int i = 0; i < 2; i++){
        int e = i * 256 + t;
        int kk = e >> 4, c4 = (e & 15) << 2;
        float4 v = make_float4(0.f, 0.f, 0.f, 0.f);
        if (k0 + kk < K) v = *(const float4*)(W + (size_t)(k0 + kk) * ldw + c4);
        *(float4*)&Wl[kk][c4] = v;
      }
      #pragma unroll
      for (int i = 0; i < RPT / 2; i++){
        int e = i * 256 + t;
        int r = e >> 3, c4 = (e & 7) << 2;
        int n = nbase + r;
        float4 v = make_float4(0.f, 0.f, 0.f, 0.f);
        if (n < nrows && k0 + c4 < K) v = *(const float4*)(A + (size_t)n * lda + k0 + c4);
        At[c4 + 0][r] = v.x;
        At[c4 + 1][r] = v.y;
        At[c4 + 2][r] = v.z;
        At[c4 + 3][r] = v.w;
      }
      __syncthreads();
      #pragma unroll 4
      for (int k = 0; k < 32; k++){
        float4 wv = *(const float4*)&Wl[k][tc * 4];
        const float* pw = (const float*)&wv;
        #pragma unroll
        for (int jj = 0; jj < RPT / 4; jj++){
          float4 av = *(const float4*)&At[k][tr * RPT + jj * 4];
          const float* pa = (const float*)&av;
          #pragma unroll
          for (int j = 0; j < 4; j++)
            #pragma unroll
            for (int i = 0; i < 4; i++)
              acc[jj * 4 + j][i] = fmaf(pa[j], pw[i], acc[jj * 4 + j][i]);
        }
      }
      __syncthreads();
    }
  }

  float b0 = bias[tc * 4 + 0], b1 = bias[tc * 4 + 1];
  float b2 = bias[tc * 4 + 2], b3 = bias[tc * 4 + 3];
  // per-thread logits weights: wa[(tc*4+i)*4 + h]
  float4 ws0, ws1, ws2, ws3, wd0, wd1, wd2, wd3;
  if (LOGITS){
    ws0 = *(const float4*)(wa_s + (tc*4+0)*4); wd0 = *(const float4*)(wa_d + (tc*4+0)*4);
    ws1 = *(const float4*)(wa_s + (tc*4+1)*4); wd1 = *(const float4*)(wa_d + (tc*4+1)*4);
    ws2 = *(const float4*)(wa_s + (tc*4+2)*4); wd2 = *(const float4*)(wa_d + (tc*4+2)*4);
    ws3 = *(const float4*)(wa_s + (tc*4+3)*4); wd3 = *(const float4*)(wa_d + (tc*4+3)*4);
  }
  #pragma unroll
  for (int j = 0; j < RPT; j++){
    int n = nbase + tr * RPT + j;
    float y0 = acc[j][0] + b0, y1 = acc[j][1] + b1;
    float y2 = acc[j][2] + b2, y3 = acc[j][3] + b3;
    if (ELU){ y0 = eluf(y0); y1 = eluf(y1); y2 = eluf(y2); y3 = eluf(y3); }
    if (n < nrows)
      *(float4*)(Y + (size_t)n * ldy + tc * 4) = make_float4(y0, y1, y2, y3);
    if (LOGITS){
      float s0 = y0*ws0.x + y1*ws1.x + y2*ws2.x + y3*ws3.x;
      float s1 = y0*ws0.y + y1*ws1.y + y2*ws2.y + y3*ws3.y;
      float s2 = y0*ws0.z + y1*ws1.z + y2*ws2.z + y3*ws3.z;
      float s3 = y0*ws0.w + y1*ws1.w + y2*ws2.w + y3*ws3.w;
      float d0 = y0*wd0.x + y1*wd1.x + y2*wd2.x + y3*wd3.x;
      float d1 = y0*wd0.y + y1*wd1.y + y2*wd2.y + y3*wd3.y;
      float d2 = y0*wd0.z + y1*wd1.z + y2*wd2.z + y3*wd3.z;
      float d3 = y0*wd0.w + y1*wd1.w + y2*wd2.w + y3*wd3.w;
      #pragma unroll
      for (int o = 1; o < 16; o <<= 1){
        s0 += __shfl_xor(s0, o); s1 += __shfl_xor(s1, o);
        s2 += __shfl_xor(s2, o); s3 += __shfl_xor(s3, o);
        d0 += __shfl_xor(d0, o); d1 += __shfl_xor(d1, o);
        d2 += __shfl_xor(d2, o); d3 += __shfl_xor(d3, o);
      }
      if (tc == 0 && n < nrows){
        *(float4*)(as_ + n * 4) = make_float4(s0, s1, s2, s3);
        *(float4*)(ad_ + n * 4) = make_float4(d0, d1, d2, d3);
      }
    }
  }
}

// ---------------- generic bf16-split MFMA GEMM (GAT1 block-diag) ----------------

template<int KSTEPS, bool ELU, bool BIAS>
__global__ __launch_bounds__(256) void gemm_mfma_kernel(
    const float* __restrict__ A, int lda, int acgoff,
    const unsigned short* __restrict__ Bhi, const unsigned short* __restrict__ Blo,
    const float* __restrict__ bias, float* __restrict__ Y, int ldy)
{
  int t = threadIdx.x;
  int lane = t & 63, wv = t >> 6;
  int cg = blockIdx.x;
  int mbase = blockIdx.y * 256 + wv * 64;
  int fr = lane & 15;
  int ksub = (lane >> 4) << 3;
  const float* Ab = A + (size_t)cg * acgoff;
  f32x4 acc[4][4];
  #pragma unroll
  for (int mi = 0; mi < 4; mi++)
    #pragma unroll
    for (int ni = 0; ni < 4; ni++)
      acc[mi][ni] = (f32x4){0.f, 0.f, 0.f, 0.f};

  #pragma unroll
  for (int ks = 0; ks < KSTEPS; ks++){
    short8v ahi[4], alo[4];
    #pragma unroll
    for (int mi = 0; mi < 4; mi++){
      int r = mbase + mi * 16 + fr;
      float av[8];
      if (r < NN){
        float4 p0 = *(const float4*)(Ab + (size_t)r * lda + ks * 32 + ksub);
        float4 p1 = *(const float4*)(Ab + (size_t)r * lda + ks * 32 + ksub + 4);
        av[0] = p0.x; av[1] = p0.y; av[2] = p0.z; av[3] = p0.w;
        av[4] = p1.x; av[5] = p1.y; av[6] = p1.z; av[7] = p1.w;
      } else {
        #pragma unroll
        for (int j = 0; j < 8; j++) av[j] = 0.f;
      }
      #pragma unroll
      for (int j = 0; j < 8; j++){
        unsigned short h = f2bf(av[j]);
        float res = av[j] - bf2f(h);
        ahi[mi][j] = (short)h;
        alo[mi][j] = (short)f2bf(res);
      }
    }
    #pragma unroll
    for (int ni = 0; ni < 4; ni++){
      size_t boff = ((((size_t)(cg * 4 + ni)) * KSTEPS + ks) * 64 + lane) * 8;
      short8v bh = *(const short8v*)(Bhi + boff);
      short8v bl = *(const short8v*)(Blo + boff);
      #pragma unroll
      for (int mi = 0; mi < 4; mi++){
        acc[mi][ni] = __builtin_amdgcn_mfma_f32_16x16x32_bf16(ahi[mi], bh, acc[mi][ni], 0, 0, 0);
        acc[mi][ni] = __builtin_amdgcn_mfma_f32_16x16x32_bf16(ahi[mi], bl, acc[mi][ni], 0, 0, 0);
        acc[mi][ni] = __builtin_amdgcn_mfma_f32_16x16x32_bf16(alo[mi], bh, acc[mi][ni], 0, 0, 0);
      }
    }
  }
  int crow = (lane >> 4) << 2;
  #pragma unroll
  for (int mi = 0; mi < 4; mi++){
    #pragma unroll
    for (int reg = 0; reg < 4; reg++){
      int r = mbase + mi * 16 + crow + reg;
      if (r < NN){
        #pragma unroll
        for (int ni = 0; ni < 4; ni++){
          float y = acc[mi][ni][reg];
          if (BIAS) y += bias[cg * 64 + ni * 16 + fr];
          if (ELU)  y = eluf(y);
          Y[(size_t)r * ldy + cg * 64 + ni * 16 + fr] = y;
        }
      }
    }
  }
}

// ---------------- L3 fused MFMA GEMM, 2-way of-split ----------------
// grid (2 of-pairs, 469 row-tiles); wave = 16 rows x 160 cols (2 ofs x 5 frags).
// Epilogue: xr[n,r,col] = sum_b comp2[r,b]*accb (bf16); rootb[n,col] (fp32).

__global__ __launch_bounds__(256) void gemm_l3_fused_kernel(
    const float* __restrict__ A,
    const unsigned short* __restrict__ Bhi, const unsigned short* __restrict__ Blo,
    const float* __restrict__ comp2,
    unsigned short* __restrict__ xr, float* __restrict__ rootb)
{
  int t = threadIdx.x;
  int lane = t & 63, wv = t >> 6;
  int of2 = blockIdx.x;                 // 0..1 -> ofs {2*of2, 2*of2+1}
  int mbase = blockIdx.y * 64 + wv * 16;
  int fr = lane & 15;
  int ksub = (lane >> 4) << 3;
  f32x4 acc[2][5];
  #pragma unroll
  for (int o = 0; o < 2; o++)
    #pragma unroll
    for (int b = 0; b < 5; b++) acc[o][b] = (f32x4){0.f, 0.f, 0.f, 0.f};

  int ar = mbase + fr;
  bool arok = (ar < NN);
  for (int ks = 0; ks < 8; ks++){
    float av[8];
    if (arok){
      float4 p0 = *(const float4*)(A + (size_t)ar * 256 + ks * 32 + ksub);
      float4 p1 = *(const float4*)(A + (size_t)ar * 256 + ks * 32 + ksub + 4);
      av[0] = p0.x; av[1] = p0.y; av[2] = p0.z; av[3] = p0.w;
      av[4] = p1.x; av[5] = p1.y; av[6] = p1.z; av[7] = p1.w;
    } else {
      #pragma unroll
      for (int j = 0; j < 8; j++) av[j] = 0.f;
    }
    short8v ahi, alo;
    #pragma unroll
    for (int j = 0; j < 8; j++){
      unsigned short h = f2bf(av[j]);
      float res = av[j] - bf2f(h);
      ahi[j] = (short)h;
      alo[j] = (short)f2bf(res);
    }
    #pragma unroll
    for (int o = 0; o < 2; o++){
      #pragma unroll
      for (int b = 0; b < 5; b++){
        int nig = b * 4 + of2 * 2 + o;   // b<4: basis, b=4: root
        size_t boff = (((size_t)nig * 8 + ks) * 64 + lane) * 8;
        short8v bh = *(const short8v*)(Bhi + boff);
        short8v bl = *(const short8v*)(Blo + boff);
        acc[o][b] = __builtin_amdgcn_mfma_f32_16x16x32_bf16(ahi, bh, acc[o][b], 0, 0, 0);
        acc[o][b] = __builtin_amdgcn_mfma_f32_16x16x32_bf16(ahi, bl, acc[o][b], 0, 0, 0);
        acc[o][b] = __builtin_amdgcn_mfma_f32_16x16x32_bf16(alo, bh, acc[o][b], 0, 0, 0);
      }
    }
  }

  float cp[32];
  #pragma unroll
  for (int i = 0; i < 32; i++) cp[i] = comp2[i];
  int crow = (lane >> 4) << 2;
  #pragma unroll
  for (int reg = 0; reg < 4; reg++){
    int r = mbase + crow + reg;
    if (r >= NN) continue;
    #pragma unroll
    for (int o = 0; o < 2; o++){
      int col = (of2 * 2 + o) * 16 + fr;
      float b0 = acc[o][0][reg], b1 = acc[o][1][reg];
      float b2 = acc[o][2][reg], b3 = acc[o][3][reg];
      rootb[(size_t)r * 64 + col] = acc[o][4][reg];
      #pragma unroll
      for (int rr = 0; rr < 8; rr++){
        float m = cp[rr*4+0]*b0 + cp[rr*4+1]*b1 + cp[rr*4+2]*b2 + cp[rr*4+3]*b3;
        xr[((size_t)r * 8 + rr) * 64 + col] = f2bf(m);
      }
    }
  }
}

// ---------------- GAT1 aggregate: 4 edge-groups x 16 ch-lanes, 4 heads per lane ----------------

__global__ void gat1_agg_kernel(const float* __restrict__ h1, const float* __restrict__ as_,
                                const float* __restrict__ ad_, const int* __restrict__ offs,
                                const int* __restrict__ csr_src, float* __restrict__ aggG){
  int wid  = (blockIdx.x * blockDim.x + threadIdx.x) >> 6;
  int lane = threadIdx.x & 63;
  if (wid >= NN) return;
  int n0 = offs[wid], n1 = offs[wid + 1];
  int h = lane & 3;
  float adn_s = ad_[wid * 4 + h];
  float m = leakyf(as_[wid * 4 + h] + adn_s);
  for (int k = n0 + (lane >> 2); k < n1; k += 16){
    int s = csr_src[k];
    m = fmaxf(m, leakyf(as_[s * 4 + h] + adn_s));
  }
  #pragma unroll
  for (int o = 4; o < 64; o <<= 1) m = fmaxf(m, __shfl_xor(m, o));
  float m0 = __shfl(m, 0), m1 = __shfl(m, 1), m2 = __shfl(m, 2), m3 = __shfl(m, 3);
  int q = lane & 15, eg = lane >> 4;
  F4 adn = ld4(ad_ + (size_t)wid * 4);
  float den0 = 0.f, den1 = 0.f, den2 = 0.f, den3 = 0.f;
  float4 ac0 = make_float4(0.f,0.f,0.f,0.f), ac1 = ac0, ac2 = ac0, ac3 = ac0;
  for (int k = n0 + eg; k < n1; k += 4){
    int s = csr_src[k];
    F4 a = ld4(as_ + (size_t)s * 4);
    float p0 = expf(leakyf(a.x + adn.x) - m0);
    float p1 = expf(leakyf(a.y + adn.y) - m1);
    float p2 = expf(leakyf(a.z + adn.z) - m2);
    float p3 = expf(leakyf(a.w + adn.w) - m3);
    den0 += p0; den1 += p1; den2 += p2; den3 += p3;
    float4 v = *(const float4*)(h1 + (size_t)s * 64 + q * 4);
    ac0.x += p0*v.x; ac0.y += p0*v.y; ac0.z += p0*v.z; ac0.w += p0*v.w;
    ac1.x += p1*v.x; ac1.y += p1*v.y; ac1.z += p1*v.z; ac1.w += p1*v.w;
    ac2.x += p2*v.x; ac2.y += p2*v.y; ac2.z += p2*v.z; ac2.w += p2*v.w;
    ac3.x += p3*v.x; ac3.y += p3*v.y; ac3.z += p3*v.z; ac3.w += p3*v.w;
  }
  #pragma unroll
  for (int o = 16; o < 64; o <<= 1){
    den0 += __shfl_xor(den0, o); den1 += __shfl_xor(den1, o);
    den2 += __shfl_xor(den2, o); den3 += __shfl_xor(den3, o);
  }
  ac0 = redeg16(ac0); ac1 = redeg16(ac1); ac2 = redeg16(ac2); ac3 = redeg16(ac3);
  F4 asn = ld4(as_ + (size_t)wid * 4);
  float ps0 = expf(leakyf(asn.x + adn.x) - m0);
  float ps1 = expf(leakyf(asn.y + adn.y) - m1);
  float ps2 = expf(leakyf(asn.z + adn.z) - m2);
  float ps3 = expf(leakyf(asn.w + adn.w) - m3);
  if (lane < 16){
    float4 v = *(const float4*)(h1 + (size_t)wid * 64 + q * 4);
    float i0 = 1.f / (den0 + ps0), i1 = 1.f / (den1 + ps1);
    float i2 = 1.f / (den2 + ps2), i3 = 1.f / (den3 + ps3);
    float* ag = aggG + (size_t)wid * 256 + q * 4;
    *(float4*)(ag)       = make_float4((ac0.x+ps0*v.x)*i0, (ac0.y+ps0*v.y)*i0, (ac0.z+ps0*v.z)*i0, (ac0.w+ps0*v.w)*i0);
    *(float4*)(ag + 64)  = make_float4((ac1.x+ps1*v.x)*i1, (ac1.y+ps1*v.y)*i1, (ac1.z+ps1*v.z)*i1, (ac1.w+ps1*v.w)*i1);
    *(float4*)(ag + 128) = make_float4((ac2.x+ps2*v.x)*i2, (ac2.y+ps2*v.y)*i2, (ac2.z+ps2*v.z)*i2, (ac2.w+ps2*v.w)*i2);
    *(float4*)(ag + 192) = make_float4((ac3.x+ps3*v.x)*i3, (ac3.y+ps3*v.y)*i3, (ac3.z+ps3*v.z)*i3, (ac3.w+ps3*v.w)*i3);
  }
}

// ---------------- layer-3 aggregate: 8 edge-groups x 8 ch-lanes (ushort8 gathers) ----------

__global__ void rgcn2_agg_kernel(const unsigned short* __restrict__ xr,
                                 const float* __restrict__ rootb,
                                 const float* __restrict__ bias, const int* __restrict__ offs,
                                 const int* __restrict__ csr_src, const int* __restrict__ csr_et,
                                 float* __restrict__ h3){
  int wid  = (blockIdx.x * blockDim.x + threadIdx.x) >> 6;
  int lane = threadIdx.x & 63;
  if (wid >= NN) return;
  int q = lane & 7, eg = lane >> 3;
  int n0 = offs[wid], n1 = offs[wid + 1];
  float a[8];
  #pragma unroll
  for (int j = 0; j < 8; j++) a[j] = 0.f;
  for (int k = n0 + eg; k < n1; k += 8){
    int s = csr_src[k], e = csr_et[k];
    short8v u = *(const short8v*)(xr + ((size_t)s * 8 + e) * 64 + q * 8);
    #pragma unroll
    for (int j = 0; j < 8; j++) a[j] += bf2f((unsigned short)u[j]);
  }
  #pragma unroll
  for (int o = 8; o < 64; o <<= 1){
    #pragma unroll
    for (int j = 0; j < 8; j++) a[j] += __shfl_xor(a[j], o);
  }
  int dg = n1 - n0;
  float sc = 1.f / (float)(dg > 0 ? dg : 1);
  if (lane < 8){
    const float* rb = rootb + (size_t)wid * 64 + q * 8;
    float4 r0 = *(const float4*)(rb);
    float4 r1 = *(const float4*)(rb + 4);
    float4 b0 = *(const float4*)(bias + q * 8);
    float4 b1 = *(const float4*)(bias + q * 8 + 4);
    float* hp = h3 + (size_t)wid * 64 + q * 8;
    *(float4*)(hp)     = make_float4(eluf(a[0]*sc + r0.x + b0.x), eluf(a[1]*sc + r0.y + b0.y),
                                     eluf(a[2]*sc + r0.z + b0.z), eluf(a[3]*sc + r0.w + b0.w));
    *(float4*)(hp + 4) = make_float4(eluf(a[4]*sc + r1.x + b1.x), eluf(a[5]*sc + r1.y + b1.y),
                                     eluf(a[6]*sc + r1.z + b1.z), eluf(a[7]*sc + r1.w + b1.w));
  }
}

// ---------------- GAT2 ----------------

__global__ void gat_lin2_kernel(const float* __restrict__ h, const float* __restrict__ W,
                                const float* __restrict__ atts, const float* __restrict__ attd,
                                float* __restrict__ hw, float* __restrict__ as_, float* __restrict__ ad_){
  int wid  = (blockIdx.x * blockDim.x + threadIdx.x) >> 6;
  int lane = threadIdx.x & 63;
  if (wid >= NN) return;
  float acc = 0.f;
  if (lane < 12){
    const float* hr = h + (size_t)wid * 64;
    const float* Wc = W + lane;
    #pragma unroll 8
    for (int i = 0; i < 64; i++) acc += hr[i] * Wc[(size_t)i * 12];
    hw[(size_t)wid * 12 + lane] = acc;
  }
  float ts = (lane < 12) ? acc * atts[lane] : 0.f;
  float td = (lane < 12) ? acc * attd[lane] : 0.f;
  int b = (lane < 4) ? lane * 3 : 0;
  float s0 = __shfl(ts, b) + __shfl(ts, b + 1) + __shfl(ts, b + 2);
  float d0 = __shfl(td, b) + __shfl(td, b + 1) + __shfl(td, b + 2);
  if (lane < 4){ as_[wid * 4 + lane] = s0; ad_[wid * 4 + lane] = d0; }
}

__global__ void gat2_final_kernel(const float* __restrict__ hw, const float* __restrict__ as_,
                                  const float* __restrict__ ad_, const float* __restrict__ bg2,
                                  const int* __restrict__ offs, const int* __restrict__ csr_src,
                                  float* __restrict__ out){
  int wid  = (blockIdx.x * blockDim.x + threadIdx.x) >> 6;
  int lane = threadIdx.x & 63;
  if (wid >= NN) return;
  int n0 = offs[wid], n1 = offs[wid + 1];
  F4 adn = ld4(ad_ + (size_t)wid * 4);
  F4 asn = ld4(as_ + (size_t)wid * 4);
  F4 es{leakyf(asn.x + adn.x), leakyf(asn.y + adn.y), leakyf(asn.z + adn.z), leakyf(asn.w + adn.w)};
  F4 m = es;
  for (int k = n0 + lane; k < n1; k += 64){
    int s = csr_src[k];
    F4 a = ld4(as_ + (size_t)s * 4);
    m.x = fmaxf(m.x, leakyf(a.x + adn.x));
    m.y = fmaxf(m.y, leakyf(a.y + adn.y));
    m.z = fmaxf(m.z, leakyf(a.z + adn.z));
    m.w = fmaxf(m.w, leakyf(a.w + adn.w));
  }
  #pragma unroll
  for (int o = 32; o; o >>= 1){
    m.x = fmaxf(m.x, __shfl_xor(m.x, o));
    m.y = fmaxf(m.y, __shfl_xor(m.y, o));
    m.z = fmaxf(m.z, __shfl_xor(m.z, o));
    m.w = fmaxf(m.w, __shfl_xor(m.w, o));
  }
  F4 ps{expf(es.x - m.x), expf(es.y - m.y), expf(es.z - m.z), expf(es.w - m.w)};
  float acc[12];
  #pragma unroll
  for (int j = 0; j < 12; j++) acc[j] = 0.f;
  F4 denp{0.f, 0.f, 0.f, 0.f};
  for (int k = n0 + lane; k < n1; k += 64){
    int s = csr_src[k];
    F4 a = ld4(as_ + (size_t)s * 4);
    F4 p{expf(leakyf(a.x + adn.x) - m.x), expf(leakyf(a.y + adn.y) - m.y),
         expf(leakyf(a.z + adn.z) - m.z), expf(leakyf(a.w + adn.w) - m.w)};
    denp.x += p.x; denp.y += p.y; denp.z += p.z; denp.w += p.w;
    const float* hb = hw + (size_t)s * 12;
    F4 h0 = ld4(hb), h1 = ld4(hb + 4), h2 = ld4(hb + 8);
    acc[0] += p.x * h0.x; acc[1]  += p.x * h0.y; acc[2]  += p.x * h0.z;
    acc[3] += p.y * h0.w; acc[4]  += p.y * h1.x; acc[5]  += p.y * h1.y;
    acc[6] += p.z * h1.z; acc[7]  += p.z * h1.w; acc[8]  += p.z * h2.x;
    acc[9] += p.w * h2.y; acc[10] += p.w * h2.z; acc[11] += p.w * h2.w;
  }
  #pragma unroll
  for (int o = 32; o; o >>= 1){
    denp.x += __shfl_xor(denp.x, o);
    denp.y += __shfl_xor(denp.y, o);
    denp.z += __shfl_xor(denp.z, o);
    denp.w += __shfl_xor(denp.w, o);
    #pragma unroll
    for (int j = 0; j < 12; j++) acc[j] += __shfl_xor(acc[j], o);
  }
  if (lane == 0){
    const float* hn = hw + (size_t)wid * 12;
    float dn[4]  = {denp.x + ps.x, denp.y + ps.y, denp.z + ps.z, denp.w + ps.w};
    float psv[4] = {ps.x, ps.y, ps.z, ps.w};
    float tot = 0.f;
    #pragma unroll
    for (int h_ = 0; h_ < 4; h_++){
      #pragma unroll
      for (int c = 0; c < 3; c++){
        float num = acc[h_ * 3 + c] + psv[h_] * hn[h_ * 3 + c];
        tot += num / dn[h_];
      }
    }
    tot = tot / 12.f + (bg2[0] + bg2[1] + bg2[2]) / 3.f;
    out[wid] = tanhf(tot);
  }
}

// ---------------- launch ----------------

extern "C" void kernel_launch(void* const* d_in, const int* in_sizes, int n_in,
                              void* d_out, int out_size, void* d_ws, size_t ws_size,
                              hipStream_t stream){
  const float* x      = (const float*)d_in[0];
  const int*   ei     = (const int*)d_in[1];
  const int*   et     = (const int*)d_in[2];
  const float* basis1 = (const float*)d_in[3];
  const float* comp1  = (const float*)d_in[4];
  const float* root1  = (const float*)d_in[5];
  const float* brg1   = (const float*)d_in[6];
  const float* Wg1    = (const float*)d_in[7];
  const float* atts1  = (const float*)d_in[8];
  const float* attd1  = (const float*)d_in[9];
  const float* bg1    = (const float*)d_in[10];
  const float* basis2 = (const float*)d_in[11];
  const float* comp2  = (const float*)d_in[12];
  const float* root2  = (const float*)d_in[13];
  const float* brg2   = (const float*)d_in[14];
  const float* Wg2    = (const float*)d_in[15];
  const float* atts2  = (const float*)d_in[16];
  const float* attd2  = (const float*)d_in[17];
  const float* bg2    = (const float*)d_in[18];
  float* out = (float*)d_out;

  const int* src = ei;
  const int* dst = ei + NE;

  char* ws = (char*)d_ws;
  size_t off = 0;
  auto alloc = [&](size_t bytes) -> void* {
    void* p = ws + off;
    off = (off + bytes + 255) & ~(size_t)255;
    return p;
  };
  // persistent
  int*   deg     = (int*)alloc((size_t)NN * 4);
  int*   cursor  = (int*)alloc((size_t)NN * 4);
  int*   offs    = (int*)alloc((size_t)(NN + 1) * 4);
  int*   bsum    = (int*)alloc((size_t)256 * 4);
  int*   csr_src = (int*)alloc((size_t)NE * 4);
  int*   csr_et  = (int*)alloc((size_t)NE * 4);
  unsigned short* Bhi2 = (unsigned short*)alloc((size_t)81920 * 2);  // L3: 20*8*64*8
  unsigned short* Blo2 = (unsigned short*)alloc((size_t)81920 * 2);
  unsigned short* Bhi1 = (unsigned short*)alloc((size_t)16384 * 2);  // GAT1: 16*2*64*8
  unsigned short* Blo1 = (unsigned short*)alloc((size_t)16384 * 2);
  float* wa_s    = (float*)alloc((size_t)256 * 4);
  float* wa_d    = (float*)alloc((size_t)256 * 4);
  float* h1      = (float*)alloc((size_t)NN * 64 * 4);
  float* h2      = (float*)alloc((size_t)NN * 256 * 4);
  float* h3      = (float*)alloc((size_t)NN * 64 * 4);
  float* hw2     = (float*)alloc((size_t)NN * 12 * 4);
  float* as1     = (float*)alloc((size_t)NN * 4 * 4);
  float* ad1     = (float*)alloc((size_t)NN * 4 * 4);
  float* as2     = (float*)alloc((size_t)NN * 4 * 4);
  float* ad2     = (float*)alloc((size_t)NN * 4 * 4);
  // scratch union S (NN*384 floats):
  //   agg1[NN*128] -> aggG[NN*256] -> { xr bf16 [NN*512] (= NN*256 floats), rootb [NN*64] }
  float* S       = (float*)alloc((size_t)NN * 384 * 4);
  float* agg1    = S;
  float* aggG    = S;
  unsigned short* xr = (unsigned short*)S;          // NN*512 ushorts = NN*256 floats
  float* rootb   = S + (size_t)NN * 256;            // NN*64 floats
  (void)ws_size; (void)n_in; (void)in_sizes; (void)out_size;

  const int BLK = 256;
  int gridN   = (NN + BLK - 1) / BLK;
  int gridE   = (NE + BLK - 1) / BLK;
  int gridW   = (NN + 3) / 4;
  int gridM64 = (NN + 63) / 64;     // 469
  int gridM256= (NN + 255) / 256;   // 118

  // CSR build + weight prep
  zero2_kernel<<<gridN, BLK, 0, stream>>>(deg, cursor, NN);
  count_kernel<<<gridE, BLK, 0, stream>>>(dst, deg, NE);
  packB2_kernel<<<(10240 + 255) / 256, BLK, 0, stream>>>(basis2, root2, Bhi2, Blo2);
  packB_kernel<<<(2048 + 255) / 256, BLK, 0, stream>>>(Wg1, 256, 2, 2048, Bhi1, Blo1);
  wa_kernel<<<1, BLK, 0, stream>>>(Wg1, atts1, attd1, wa_s, wa_d);
  scan1_kernel<<<gridN, BLK, 0, stream>>>(deg, offs, bsum);
  scan2_kernel<<<1, BLK, 0, stream>>>(bsum, gridN);
  scan3_kernel<<<gridN, BLK, 0, stream>>>(bsum, offs);
  scatter_kernel<<<gridE, BLK, 0, stream>>>(src, dst, et, offs, cursor, csr_src, csr_et, NE);

  // Layer 1: RGCN (32 -> 64) + elu, GAT1 logits fused into epilogue
  agg1_kernel<<<gridW, BLK, 0, stream>>>(x, comp1, offs, csr_src, csr_et, agg1);
  gemmT_kernel<4, true, true><<<gridM64, BLK, 0, stream>>>(
      agg1, 128, 128, basis1, 64,
      x, 32, 32, root1, 64,
      brg1, h1, 64, NN, wa_s, wa_d, as1, ad1);

  // Layer 2: GAT (64 -> 256 concat) + elu: aggregate h1 -> MFMA block-diag GEMM
  gat1_agg_kernel<<<gridW, BLK, 0, stream>>>(h1, as1, ad1, offs, csr_src, aggG);
  gemm_mfma_kernel<2, true, true><<<dim3(4, gridM256), BLK, 0, stream>>>(
      aggG, 256, 64, Bhi1, Blo1, bg1, h2, 256);

  // Layer 3: RGCN (256 -> 64) + elu: fused MFMA transform (of-split x2) -> xr + root
  gemm_l3_fused_kernel<<<dim3(2, gridM64), BLK, 0, stream>>>(h2, Bhi2, Blo2, comp2, xr, rootb);
  rgcn2_agg_kernel<<<gridW, BLK, 0, stream>>>(xr, rootb, brg2, offs, csr_src, csr_et, h3);

  // Layer 4: GAT (64 -> 4x3, mean heads) + mean classes + tanh
  gat_lin2_kernel<<<gridW, BLK, 0, stream>>>(h3, Wg2, atts2, attd2, hw2, as2, ad2);
  gat2_final_kernel<<<gridW, BLK, 0, stream>>>(hw2, as2, ad2, bg2, offs, csr_src, out);
}

// Round 18
// 322.063 us; speedup vs baseline: 1.0138x; 1.0138x over previous
//
#include <hip/hip_runtime.h>
#include <cstdint>
#include <cstddef>

#define NN 30000
#define NE 480000

typedef __attribute__((ext_vector_type(8))) short short8v;
typedef __attribute__((ext_vector_type(4))) float f32x4;

__device__ __forceinline__ float leakyf(float x){ return x > 0.f ? x : 0.2f * x; }
__device__ __forceinline__ float eluf(float x){ return x > 0.f ? x : expm1f(x); }

__device__ __forceinline__ float bf2f(unsigned short u){
  return __uint_as_float(((unsigned)u) << 16);
}
__device__ __forceinline__ unsigned short f2bf(float f){
  unsigned x = __float_as_uint(f);
  unsigned r = (x + 0x7FFFu + ((x >> 16) & 1u)) >> 16;
  return (unsigned short)r;
}

struct F4 { float x, y, z, w; };

__device__ __forceinline__ F4 ld4(const float* p){
  float4 v = *(const float4*)p;
  return F4{v.x, v.y, v.z, v.w};
}

__device__ __forceinline__ float4 redeg16(float4 v){
  v.x += __shfl_xor(v.x, 16); v.y += __shfl_xor(v.y, 16);
  v.z += __shfl_xor(v.z, 16); v.w += __shfl_xor(v.w, 16);
  v.x += __shfl_xor(v.x, 32); v.y += __shfl_xor(v.y, 32);
  v.z += __shfl_xor(v.z, 32); v.w += __shfl_xor(v.w, 32);
  return v;
}

// ---------------- CSR build ----------------

__global__ void zero2_kernel(int* __restrict__ a, int* __restrict__ b, int n){
  int i = blockIdx.x * blockDim.x + threadIdx.x;
  if (i < n){ a[i] = 0; b[i] = 0; }
}

__global__ void count_kernel(const int* __restrict__ dst, int* __restrict__ deg, int E){
  int i = blockIdx.x * blockDim.x + threadIdx.x;
  if (i < E) atomicAdd(&deg[dst[i]], 1);
}

__global__ void scan1_kernel(const int* __restrict__ deg, int* __restrict__ offs,
                             int* __restrict__ bsum){
  __shared__ int sh[256];
  int blk = blockIdx.x, t = threadIdx.x, i = blk * 256 + t;
  int v = (i < NN) ? deg[i] : 0;
  sh[t] = v; __syncthreads();
  for (int o = 1; o < 256; o <<= 1){
    int tv = (t >= o) ? sh[t - o] : 0;
    __syncthreads();
    sh[t] += tv;
    __syncthreads();
  }
  if (i < NN) offs[i + 1] = sh[t];
  if (t == 255) bsum[blk] = sh[255];
}

__global__ void scan2_kernel(int* __restrict__ bsum, int nb){
  __shared__ int sh[256];
  int t = threadIdx.x;
  int v = (t < nb) ? bsum[t] : 0;
  sh[t] = v; __syncthreads();
  for (int o = 1; o < 256; o <<= 1){
    int tv = (t >= o) ? sh[t - o] : 0;
    __syncthreads();
    sh[t] += tv;
    __syncthreads();
  }
  if (t < nb) bsum[t] = sh[t];
}

__global__ void scan3_kernel(const int* __restrict__ bsum, int* __restrict__ offs){
  int i = blockIdx.x * 256 + threadIdx.x;
  if (i == 0) offs[0] = 0;
  if (i < NN){
    int blk = i >> 8;
    int add = blk ? bsum[blk - 1] : 0;
    offs[i + 1] += add;
  }
}

__global__ void scatter_kernel(const int* __restrict__ src, const int* __restrict__ dst,
                               const int* __restrict__ et, const int* __restrict__ offs,
                               int* __restrict__ cursor, int* __restrict__ csr_src,
                               int* __restrict__ csr_et, int E){
  int i = blockIdx.x * blockDim.x + threadIdx.x;
  if (i < E){
    int d = dst[i];
    int pos = offs[d] + atomicAdd(&cursor[d], 1);
    csr_src[pos] = src[i];
    csr_et[pos]  = et[i];
  }
}

// ---------------- weight prep ----------------

// L3 B-fragments straight from basis2/root2 (virtual Wcat cols: 0..255 basis, 256..319 root).
__global__ void packB2_kernel(const float* __restrict__ basis2, const float* __restrict__ root2,
                              unsigned short* __restrict__ Bhi, unsigned short* __restrict__ Blo){
  int idx = blockIdx.x * 256 + threadIdx.x;
  if (idx >= 10240) return;
  int lane = idx & 63;
  int rest = idx >> 6;
  int ks = rest & 7;
  int nf16 = rest >> 3;                       // 0..19
  int col = nf16 * 16 + (lane & 15);
  int kbase = ks * 32 + ((lane >> 4) << 3);
  size_t obase = (size_t)idx * 8;
  #pragma unroll
  for (int j = 0; j < 8; j++){
    int k = kbase + j;
    float v;
    if (col < 256){
      int b = col >> 6, c = col & 63;
      v = basis2[((size_t)b * 256 + k) * 64 + c];
    } else {
      v = root2[(size_t)k * 64 + (col - 256)];
    }
    unsigned short h = f2bf(v);
    float res = v - bf2f(h);
    Bhi[obase + j] = h;
    Blo[obase + j] = f2bf(res);
  }
}

// generic MFMA B-fragment pack (GAT1 Wg1), bf16 hi/lo split.
__global__ void packB_kernel(const float* __restrict__ W, int ldw, int ksteps, int total,
                             unsigned short* __restrict__ Bhi, unsigned short* __restrict__ Blo){
  int idx = blockIdx.x * 256 + threadIdx.x;
  if (idx >= total) return;
  int lane = idx & 63;
  int rest = idx >> 6;
  int ks = rest % ksteps;
  int nf16 = rest / ksteps;
  int col = nf16 * 16 + (lane & 15);
  int kbase = ks * 32 + ((lane >> 4) << 3);
  size_t obase = (size_t)idx * 8;
  #pragma unroll
  for (int j = 0; j < 8; j++){
    float v = W[(size_t)(kbase + j) * ldw + col];
    unsigned short h = f2bf(v);
    float res = v - bf2f(h);
    Bhi[obase + j] = h;
    Blo[obase + j] = f2bf(res);
  }
}

// wa_s[k*4+h] = sum_c Wg1[k, h*64+c] * atts1[h,c]  (and wa_d with attd1)
__global__ void wa_kernel(const float* __restrict__ Wg1, const float* __restrict__ atts1,
                          const float* __restrict__ attd1, float* __restrict__ wa_s,
                          float* __restrict__ wa_d){
  int t = threadIdx.x;
  int k = t >> 2, h = t & 3;
  float s = 0.f, d = 0.f;
  const float* wr = Wg1 + (size_t)k * 256 + h * 64;
  const float* pa = atts1 + h * 64;
  const float* pb = attd1 + h * 64;
  #pragma unroll 8
  for (int c = 0; c < 64; c++){ s += wr[c] * pa[c]; d += wr[c] * pb[c]; }
  wa_s[k * 4 + h] = s;
  wa_d[k * 4 + h] = d;
}

// ---------------- layer-1 basis-space aggregation (4 edge-groups x float2) ----------------

__global__ void agg1_kernel(const float* __restrict__ x, const float* __restrict__ comp,
                            const int* __restrict__ offs, const int* __restrict__ csr_src,
                            const int* __restrict__ csr_et, float* __restrict__ agg){
  int wid  = (blockIdx.x * blockDim.x + threadIdx.x) >> 6;
  int lane = threadIdx.x & 63;
  if (wid >= NN) return;
  int q = lane & 15, eg = lane >> 4;
  int c2 = q * 2;
  int n0 = offs[wid], n1 = offs[wid + 1];
  float a00 = 0.f, a01 = 0.f, a10 = 0.f, a11 = 0.f;
  float a20 = 0.f, a21 = 0.f, a30 = 0.f, a31 = 0.f;
  for (int k = n0 + eg; k < n1; k += 4){
    int s = csr_src[k], e = csr_et[k];
    float2 v = *(const float2*)(x + (size_t)s * 32 + c2);
    F4 cp = ld4(comp + (size_t)e * 4);
    a00 += cp.x * v.x; a01 += cp.x * v.y;
    a10 += cp.y * v.x; a11 += cp.y * v.y;
    a20 += cp.z * v.x; a21 += cp.z * v.y;
    a30 += cp.w * v.x; a31 += cp.w * v.y;
  }
  #pragma unroll
  for (int o = 16; o < 64; o <<= 1){
    a00 += __shfl_xor(a00, o); a01 += __shfl_xor(a01, o);
    a10 += __shfl_xor(a10, o); a11 += __shfl_xor(a11, o);
    a20 += __shfl_xor(a20, o); a21 += __shfl_xor(a21, o);
    a30 += __shfl_xor(a30, o); a31 += __shfl_xor(a31, o);
  }
  int dg = n1 - n0;
  float sc = 1.f / (float)(dg > 0 ? dg : 1);
  if (lane < 16){
    float* ar = agg + (size_t)wid * 128 + c2;
    *(float2*)(ar)      = make_float2(a00 * sc, a01 * sc);
    *(float2*)(ar + 32) = make_float2(a10 * sc, a11 * sc);
    *(float2*)(ar + 64) = make_float2(a20 * sc, a21 * sc);
    *(float2*)(ar + 96) = make_float2(a30 * sc, a31 * sc);
  }
}

// ---------------- (RPT*16)-row x 64-col fused GEMM (layer 1), logits fused ----------------

template<int RPT, bool ELU, bool LOGITS>
__global__ __launch_bounds__(256) void gemmT_kernel(
    const float* __restrict__ A1, int lda1, int K1,
    const float* __restrict__ W1, int ldw1,
    const float* __restrict__ A2, int lda2, int K2,
    const float* __restrict__ W2, int ldw2,
    const float* __restrict__ bias,
    float* __restrict__ Y, int ldy,
    int nrows,
    const float* __restrict__ wa_s, const float* __restrict__ wa_d,
    float* __restrict__ as_, float* __restrict__ ad_)
{
  __shared__ float At[32][RPT * 16 + 4];
  __shared__ float Wl[32][68];
  int t = threadIdx.x;
  int tc = t & 15, tr = t >> 4;
  int nbase = blockIdx.x * (RPT * 16);
  float acc[RPT][4];
  #pragma unroll
  for (int j = 0; j < RPT; j++)
    #pragma unroll
    for (int i = 0; i < 4; i++) acc[j][i] = 0.f;

  for (int seg = 0; seg < 2; seg++){
    const float* A = seg ? A2 : A1;
    const float* W = seg ? W2 : W1;
    int lda = seg ? lda2 : lda1;
    int ldw = seg ? ldw2 : ldw1;
    int K   = seg ? K2 : K1;
    if (A == nullptr || K <= 0) continue;
    for (int k0 = 0; k0 < K; k0 += 32){
      #pragma unroll
      for (int i = 0; i < 2; i++){
        int e = i * 256 + t;
        int kk = e >> 4, c4 = (e & 15) << 2;
        float4 v = make_float4(0.f, 0.f, 0.f, 0.f);
        if (k0 + kk < K) v = *(const float4*)(W + (size_t)(k0 + kk) * ldw + c4);
        *(float4*)&Wl[kk][c4] = v;
      }
      #pragma unroll
      for (int i = 0; i < RPT / 2; i++){
        int e = i * 256 + t;
        int r = e >> 3, c4 = (e & 7) << 2;
        int n = nbase + r;
        float4 v = make_float4(0.f, 0.f, 0.f, 0.f);
        if (n < nrows && k0 + c4 < K) v = *(const float4*)(A + (size_t)n * lda + k0 + c4);
        At[c4 + 0][r] = v.x;
        At[c4 + 1][r] = v.y;
        At[c4 + 2][r] = v.z;
        At[c4 + 3][r] = v.w;
      }
      __syncthreads();
      #pragma unroll 4
      for (int k = 0; k < 32; k++){
        float4 wv = *(const float4*)&Wl[k][tc * 4];
        const float* pw = (const float*)&wv;
        #pragma unroll
        for (int jj = 0; jj < RPT / 4; jj++){
          float4 av = *(const float4*)&At[k][tr * RPT + jj * 4];
          const float* pa = (const float*)&av;
          #pragma unroll
          for (int j = 0; j < 4; j++)
            #pragma unroll
            for (int i = 0; i < 4; i++)
              acc[jj * 4 + j][i] = fmaf(pa[j], pw[i], acc[jj * 4 + j][i]);
        }
      }
      __syncthreads();
    }
  }

  float b0 = bias[tc * 4 + 0], b1 = bias[tc * 4 + 1];
  float b2 = bias[tc * 4 + 2], b3 = bias[tc * 4 + 3];
  float4 ws0, ws1, ws2, ws3, wd0, wd1, wd2, wd3;
  if (LOGITS){
    ws0 = *(const float4*)(wa_s + (tc*4+0)*4); wd0 = *(const float4*)(wa_d + (tc*4+0)*4);
    ws1 = *(const float4*)(wa_s + (tc*4+1)*4); wd1 = *(const float4*)(wa_d + (tc*4+1)*4);
    ws2 = *(const float4*)(wa_s + (tc*4+2)*4); wd2 = *(const float4*)(wa_d + (tc*4+2)*4);
    ws3 = *(const float4*)(wa_s + (tc*4+3)*4); wd3 = *(const float4*)(wa_d + (tc*4+3)*4);
  }
  #pragma unroll
  for (int j = 0; j < RPT; j++){
    int n = nbase + tr * RPT + j;
    float y0 = acc[j][0] + b0, y1 = acc[j][1] + b1;
    float y2 = acc[j][2] + b2, y3 = acc[j][3] + b3;
    if (ELU){ y0 = eluf(y0); y1 = eluf(y1); y2 = eluf(y2); y3 = eluf(y3); }
    if (n < nrows)
      *(float4*)(Y + (size_t)n * ldy + tc * 4) = make_float4(y0, y1, y2, y3);
    if (LOGITS){
      float s0 = y0*ws0.x + y1*ws1.x + y2*ws2.x + y3*ws3.x;
      float s1 = y0*ws0.y + y1*ws1.y + y2*ws2.y + y3*ws3.y;
      float s2 = y0*ws0.z + y1*ws1.z + y2*ws2.z + y3*ws3.z;
      float s3 = y0*ws0.w + y1*ws1.w + y2*ws2.w + y3*ws3.w;
      float d0 = y0*wd0.x + y1*wd1.x + y2*wd2.x + y3*wd3.x;
      float d1 = y0*wd0.y + y1*wd1.y + y2*wd2.y + y3*wd3.y;
      float d2 = y0*wd0.z + y1*wd1.z + y2*wd2.z + y3*wd3.z;
      float d3 = y0*wd0.w + y1*wd1.w + y2*wd2.w + y3*wd3.w;
      #pragma unroll
      for (int o = 1; o < 16; o <<= 1){
        s0 += __shfl_xor(s0, o); s1 += __shfl_xor(s1, o);
        s2 += __shfl_xor(s2, o); s3 += __shfl_xor(s3, o);
        d0 += __shfl_xor(d0, o); d1 += __shfl_xor(d1, o);
        d2 += __shfl_xor(d2, o); d3 += __shfl_xor(d3, o);
      }
      if (tc == 0 && n < nrows){
        *(float4*)(as_ + n * 4) = make_float4(s0, s1, s2, s3);
        *(float4*)(ad_ + n * 4) = make_float4(d0, d1, d2, d3);
      }
    }
  }
}

// ---------------- generic bf16-split MFMA GEMM (GAT1 block-diag) ----------------

template<int KSTEPS, bool ELU, bool BIAS>
__global__ __launch_bounds__(256) void gemm_mfma_kernel(
    const float* __restrict__ A, int lda, int acgoff,
    const unsigned short* __restrict__ Bhi, const unsigned short* __restrict__ Blo,
    const float* __restrict__ bias, float* __restrict__ Y, int ldy)
{
  int t = threadIdx.x;
  int lane = t & 63, wv = t >> 6;
  int cg = blockIdx.x;
  int mbase = blockIdx.y * 256 + wv * 64;
  int fr = lane & 15;
  int ksub = (lane >> 4) << 3;
  const float* Ab = A + (size_t)cg * acgoff;
  f32x4 acc[4][4];
  #pragma unroll
  for (int mi = 0; mi < 4; mi++)
    #pragma unroll
    for (int ni = 0; ni < 4; ni++)
      acc[mi][ni] = (f32x4){0.f, 0.f, 0.f, 0.f};

  #pragma unroll
  for (int ks = 0; ks < KSTEPS; ks++){
    short8v ahi[4], alo[4];
    #pragma unroll
    for (int mi = 0; mi < 4; mi++){
      int r = mbase + mi * 16 + fr;
      float av[8];
      if (r < NN){
        float4 p0 = *(const float4*)(Ab + (size_t)r * lda + ks * 32 + ksub);
        float4 p1 = *(const float4*)(Ab + (size_t)r * lda + ks * 32 + ksub + 4);
        av[0] = p0.x; av[1] = p0.y; av[2] = p0.z; av[3] = p0.w;
        av[4] = p1.x; av[5] = p1.y; av[6] = p1.z; av[7] = p1.w;
      } else {
        #pragma unroll
        for (int j = 0; j < 8; j++) av[j] = 0.f;
      }
      #pragma unroll
      for (int j = 0; j < 8; j++){
        unsigned short h = f2bf(av[j]);
        float res = av[j] - bf2f(h);
        ahi[mi][j] = (short)h;
        alo[mi][j] = (short)f2bf(res);
      }
    }
    #pragma unroll
    for (int ni = 0; ni < 4; ni++){
      size_t boff = ((((size_t)(cg * 4 + ni)) * KSTEPS + ks) * 64 + lane) * 8;
      short8v bh = *(const short8v*)(Bhi + boff);
      short8v bl = *(const short8v*)(Blo + boff);
      #pragma unroll
      for (int mi = 0; mi < 4; mi++){
        acc[mi][ni] = __builtin_amdgcn_mfma_f32_16x16x32_bf16(ahi[mi], bh, acc[mi][ni], 0, 0, 0);
        acc[mi][ni] = __builtin_amdgcn_mfma_f32_16x16x32_bf16(ahi[mi], bl, acc[mi][ni], 0, 0, 0);
        acc[mi][ni] = __builtin_amdgcn_mfma_f32_16x16x32_bf16(alo[mi], bh, acc[mi][ni], 0, 0, 0);
      }
    }
  }
  int crow = (lane >> 4) << 2;
  #pragma unroll
  for (int mi = 0; mi < 4; mi++){
    #pragma unroll
    for (int reg = 0; reg < 4; reg++){
      int r = mbase + mi * 16 + crow + reg;
      if (r < NN){
        #pragma unroll
        for (int ni = 0; ni < 4; ni++){
          float y = acc[mi][ni][reg];
          if (BIAS) y += bias[cg * 64 + ni * 16 + fr];
          if (ELU)  y = eluf(y);
          Y[(size_t)r * ldy + cg * 64 + ni * 16 + fr] = y;
        }
      }
    }
  }
}

// ---------------- L3 fused MFMA GEMM, 4-way of-split (measured best) ----------------
// grid (4 ofs, 469 row-tiles); wave = 16 rows x 80 cols (5 frags: 4 bases + root at of).
// Epilogue: xr[n,r,of*16+fr] = sum_b comp2[r,b]*accb (bf16); rootb[n,of*16+fr] (fp32).

__global__ __launch_bounds__(256) void gemm_l3_fused_kernel(
    const float* __restrict__ A,
    const unsigned short* __restrict__ Bhi, const unsigned short* __restrict__ Blo,
    const float* __restrict__ comp2,
    unsigned short* __restrict__ xr, float* __restrict__ rootb)
{
  int t = threadIdx.x;
  int lane = t & 63, wv = t >> 6;
  int of = blockIdx.x;
  int mbase = blockIdx.y * 64 + wv * 16;
  int fr = lane & 15;
  int ksub = (lane >> 4) << 3;
  f32x4 acc[5];
  #pragma unroll
  for (int b = 0; b < 5; b++) acc[b] = (f32x4){0.f, 0.f, 0.f, 0.f};

  int ar = mbase + fr;
  bool arok = (ar < NN);
  for (int ks = 0; ks < 8; ks++){
    float av[8];
    if (arok){
      float4 p0 = *(const float4*)(A + (size_t)ar * 256 + ks * 32 + ksub);
      float4 p1 = *(const float4*)(A + (size_t)ar * 256 + ks * 32 + ksub + 4);
      av[0] = p0.x; av[1] = p0.y; av[2] = p0.z; av[3] = p0.w;
      av[4] = p1.x; av[5] = p1.y; av[6] = p1.z; av[7] = p1.w;
    } else {
      #pragma unroll
      for (int j = 0; j < 8; j++) av[j] = 0.f;
    }
    short8v ahi, alo;
    #pragma unroll
    for (int j = 0; j < 8; j++){
      unsigned short h = f2bf(av[j]);
      float res = av[j] - bf2f(h);
      ahi[j] = (short)h;
      alo[j] = (short)f2bf(res);
    }
    #pragma unroll
    for (int b = 0; b < 5; b++){
      int nig = b * 4 + of;                 // b<4: basis, b=4: root
      size_t boff = (((size_t)nig * 8 + ks) * 64 + lane) * 8;
      short8v bh = *(const short8v*)(Bhi + boff);
      short8v bl = *(const short8v*)(Blo + boff);
      acc[b] = __builtin_amdgcn_mfma_f32_16x16x32_bf16(ahi, bh, acc[b], 0, 0, 0);
      acc[b] = __builtin_amdgcn_mfma_f32_16x16x32_bf16(ahi, bl, acc[b], 0, 0, 0);
      acc[b] = __builtin_amdgcn_mfma_f32_16x16x32_bf16(alo, bh, acc[b], 0, 0, 0);
    }
  }

  float cp[32];
  #pragma unroll
  for (int i = 0; i < 32; i++) cp[i] = comp2[i];
  int crow = (lane >> 4) << 2;
  int col = of * 16 + fr;
  #pragma unroll
  for (int reg = 0; reg < 4; reg++){
    int r = mbase + crow + reg;
    if (r >= NN) continue;
    float b0 = acc[0][reg], b1 = acc[1][reg], b2 = acc[2][reg], b3 = acc[3][reg];
    rootb[(size_t)r * 64 + col] = acc[4][reg];
    #pragma unroll
    for (int rr = 0; rr < 8; rr++){
      float m = cp[rr*4+0]*b0 + cp[rr*4+1]*b1 + cp[rr*4+2]*b2 + cp[rr*4+3]*b3;
      xr[((size_t)r * 8 + rr) * 64 + col] = f2bf(m);
    }
  }
}

// ---------------- GAT1 aggregate: 4 edge-groups x 16 ch-lanes, 4 heads per lane ----------------

__global__ void gat1_agg_kernel(const float* __restrict__ h1, const float* __restrict__ as_,
                                const float* __restrict__ ad_, const int* __restrict__ offs,
                                const int* __restrict__ csr_src, float* __restrict__ aggG){
  int wid  = (blockIdx.x * blockDim.x + threadIdx.x) >> 6;
  int lane = threadIdx.x & 63;
  if (wid >= NN) return;
  int n0 = offs[wid], n1 = offs[wid + 1];
  int h = lane & 3;
  float adn_s = ad_[wid * 4 + h];
  float m = leakyf(as_[wid * 4 + h] + adn_s);
  for (int k = n0 + (lane >> 2); k < n1; k += 16){
    int s = csr_src[k];
    m = fmaxf(m, leakyf(as_[s * 4 + h] + adn_s));
  }
  #pragma unroll
  for (int o = 4; o < 64; o <<= 1) m = fmaxf(m, __shfl_xor(m, o));
  float m0 = __shfl(m, 0), m1 = __shfl(m, 1), m2 = __shfl(m, 2), m3 = __shfl(m, 3);
  int q = lane & 15, eg = lane >> 4;
  F4 adn = ld4(ad_ + (size_t)wid * 4);
  float den0 = 0.f, den1 = 0.f, den2 = 0.f, den3 = 0.f;
  float4 ac0 = make_float4(0.f,0.f,0.f,0.f), ac1 = ac0, ac2 = ac0, ac3 = ac0;
  for (int k = n0 + eg; k < n1; k += 4){
    int s = csr_src[k];
    F4 a = ld4(as_ + (size_t)s * 4);
    float p0 = expf(leakyf(a.x + adn.x) - m0);
    float p1 = expf(leakyf(a.y + adn.y) - m1);
    float p2 = expf(leakyf(a.z + adn.z) - m2);
    float p3 = expf(leakyf(a.w + adn.w) - m3);
    den0 += p0; den1 += p1; den2 += p2; den3 += p3;
    float4 v = *(const float4*)(h1 + (size_t)s * 64 + q * 4);
    ac0.x += p0*v.x; ac0.y += p0*v.y; ac0.z += p0*v.z; ac0.w += p0*v.w;
    ac1.x += p1*v.x; ac1.y += p1*v.y; ac1.z += p1*v.z; ac1.w += p1*v.w;
    ac2.x += p2*v.x; ac2.y += p2*v.y; ac2.z += p2*v.z; ac2.w += p2*v.w;
    ac3.x += p3*v.x; ac3.y += p3*v.y; ac3.z += p3*v.z; ac3.w += p3*v.w;
  }
  #pragma unroll
  for (int o = 16; o < 64; o <<= 1){
    den0 += __shfl_xor(den0, o); den1 += __shfl_xor(den1, o);
    den2 += __shfl_xor(den2, o); den3 += __shfl_xor(den3, o);
  }
  ac0 = redeg16(ac0); ac1 = redeg16(ac1); ac2 = redeg16(ac2); ac3 = redeg16(ac3);
  F4 asn = ld4(as_ + (size_t)wid * 4);
  float ps0 = expf(leakyf(asn.x + adn.x) - m0);
  float ps1 = expf(leakyf(asn.y + adn.y) - m1);
  float ps2 = expf(leakyf(asn.z + adn.z) - m2);
  float ps3 = expf(leakyf(asn.w + adn.w) - m3);
  if (lane < 16){
    float4 v = *(const float4*)(h1 + (size_t)wid * 64 + q * 4);
    float i0 = 1.f / (den0 + ps0), i1 = 1.f / (den1 + ps1);
    float i2 = 1.f / (den2 + ps2), i3 = 1.f / (den3 + ps3);
    float* ag = aggG + (size_t)wid * 256 + q * 4;
    *(float4*)(ag)       = make_float4((ac0.x+ps0*v.x)*i0, (ac0.y+ps0*v.y)*i0, (ac0.z+ps0*v.z)*i0, (ac0.w+ps0*v.w)*i0);
    *(float4*)(ag + 64)  = make_float4((ac1.x+ps1*v.x)*i1, (ac1.y+ps1*v.y)*i1, (ac1.z+ps1*v.z)*i1, (ac1.w+ps1*v.w)*i1);
    *(float4*)(ag + 128) = make_float4((ac2.x+ps2*v.x)*i2, (ac2.y+ps2*v.y)*i2, (ac2.z+ps2*v.z)*i2, (ac2.w+ps2*v.w)*i2);
    *(float4*)(ag + 192) = make_float4((ac3.x+ps3*v.x)*i3, (ac3.y+ps3*v.y)*i3, (ac3.z+ps3*v.z)*i3, (ac3.w+ps3*v.w)*i3);
  }
}

// ---------------- layer-3 aggregate: 8 edge-groups x 8 ch-lanes (ushort8 gathers) ----------

__global__ void rgcn2_agg_kernel(const unsigned short* __restrict__ xr,
                                 const float* __restrict__ rootb,
                                 const float* __restrict__ bias, const int* __restrict__ offs,
                                 const int* __restrict__ csr_src, const int* __restrict__ csr_et,
                                 float* __restrict__ h3){
  int wid  = (blockIdx.x * blockDim.x + threadIdx.x) >> 6;
  int lane = threadIdx.x & 63;
  if (wid >= NN) return;
  int q = lane & 7, eg = lane >> 3;
  int n0 = offs[wid], n1 = offs[wid + 1];
  float a[8];
  #pragma unroll
  for (int j = 0; j < 8; j++) a[j] = 0.f;
  for (int k = n0 + eg; k < n1; k += 8){
    int s = csr_src[k], e = csr_et[k];
    short8v u = *(const short8v*)(xr + ((size_t)s * 8 + e) * 64 + q * 8);
    #pragma unroll
    for (int j = 0; j < 8; j++) a[j] += bf2f((unsigned short)u[j]);
  }
  #pragma unroll
  for (int o = 8; o < 64; o <<= 1){
    #pragma unroll
    for (int j = 0; j < 8; j++) a[j] += __shfl_xor(a[j], o);
  }
  int dg = n1 - n0;
  float sc = 1.f / (float)(dg > 0 ? dg : 1);
  if (lane < 8){
    const float* rb = rootb + (size_t)wid * 64 + q * 8;
    float4 r0 = *(const float4*)(rb);
    float4 r1 = *(const float4*)(rb + 4);
    float4 b0 = *(const float4*)(bias + q * 8);
    float4 b1 = *(const float4*)(bias + q * 8 + 4);
    float* hp = h3 + (size_t)wid * 64 + q * 8;
    *(float4*)(hp)     = make_float4(eluf(a[0]*sc + r0.x + b0.x), eluf(a[1]*sc + r0.y + b0.y),
                                     eluf(a[2]*sc + r0.z + b0.z), eluf(a[3]*sc + r0.w + b0.w));
    *(float4*)(hp + 4) = make_float4(eluf(a[4]*sc + r1.x + b1.x), eluf(a[5]*sc + r1.y + b1.y),
                                     eluf(a[6]*sc + r1.z + b1.z), eluf(a[7]*sc + r1.w + b1.w));
  }
}

// ---------------- GAT2 ----------------

__global__ void gat_lin2_kernel(const float* __restrict__ h, const float* __restrict__ W,
                                const float* __restrict__ atts, const float* __restrict__ attd,
                                float* __restrict__ hw, float* __restrict__ as_, float* __restrict__ ad_){
  int wid  = (blockIdx.x * blockDim.x + threadIdx.x) >> 6;
  int lane = threadIdx.x & 63;
  if (wid >= NN) return;
  float acc = 0.f;
  if (lane < 12){
    const float* hr = h + (size_t)wid * 64;
    const float* Wc = W + lane;
    #pragma unroll 8
    for (int i = 0; i < 64; i++) acc += hr[i] * Wc[(size_t)i * 12];
    hw[(size_t)wid * 12 + lane] = acc;
  }
  float ts = (lane < 12) ? acc * atts[lane] : 0.f;
  float td = (lane < 12) ? acc * attd[lane] : 0.f;
  int b = (lane < 4) ? lane * 3 : 0;
  float s0 = __shfl(ts, b) + __shfl(ts, b + 1) + __shfl(ts, b + 2);
  float d0 = __shfl(td, b) + __shfl(td, b + 1) + __shfl(td, b + 2);
  if (lane < 4){ as_[wid * 4 + lane] = s0; ad_[wid * 4 + lane] = d0; }
}

__global__ void gat2_final_kernel(const float* __restrict__ hw, const float* __restrict__ as_,
                                  const float* __restrict__ ad_, const float* __restrict__ bg2,
                                  const int* __restrict__ offs, const int* __restrict__ csr_src,
                                  float* __restrict__ out){
  int wid  = (blockIdx.x * blockDim.x + threadIdx.x) >> 6;
  int lane = threadIdx.x & 63;
  if (wid >= NN) return;
  int n0 = offs[wid], n1 = offs[wid + 1];
  F4 adn = ld4(ad_ + (size_t)wid * 4);
  F4 asn = ld4(as_ + (size_t)wid * 4);
  F4 es{leakyf(asn.x + adn.x), leakyf(asn.y + adn.y), leakyf(asn.z + adn.z), leakyf(asn.w + adn.w)};
  F4 m = es;
  for (int k = n0 + lane; k < n1; k += 64){
    int s = csr_src[k];
    F4 a = ld4(as_ + (size_t)s * 4);
    m.x = fmaxf(m.x, leakyf(a.x + adn.x));
    m.y = fmaxf(m.y, leakyf(a.y + adn.y));
    m.z = fmaxf(m.z, leakyf(a.z + adn.z));
    m.w = fmaxf(m.w, leakyf(a.w + adn.w));
  }
  #pragma unroll
  for (int o = 32; o; o >>= 1){
    m.x = fmaxf(m.x, __shfl_xor(m.x, o));
    m.y = fmaxf(m.y, __shfl_xor(m.y, o));
    m.z = fmaxf(m.z, __shfl_xor(m.z, o));
    m.w = fmaxf(m.w, __shfl_xor(m.w, o));
  }
  F4 ps{expf(es.x - m.x), expf(es.y - m.y), expf(es.z - m.z), expf(es.w - m.w)};
  float acc[12];
  #pragma unroll
  for (int j = 0; j < 12; j++) acc[j] = 0.f;
  F4 denp{0.f, 0.f, 0.f, 0.f};
  for (int k = n0 + lane; k < n1; k += 64){
    int s = csr_src[k];
    F4 a = ld4(as_ + (size_t)s * 4);
    F4 p{expf(leakyf(a.x + adn.x) - m.x), expf(leakyf(a.y + adn.y) - m.y),
         expf(leakyf(a.z + adn.z) - m.z), expf(leakyf(a.w + adn.w) - m.w)};
    denp.x += p.x; denp.y += p.y; denp.z += p.z; denp.w += p.w;
    const float* hb = hw + (size_t)s * 12;
    F4 h0 = ld4(hb), h1 = ld4(hb + 4), h2 = ld4(hb + 8);
    acc[0] += p.x * h0.x; acc[1]  += p.x * h0.y; acc[2]  += p.x * h0.z;
    acc[3] += p.y * h0.w; acc[4]  += p.y * h1.x; acc[5]  += p.y * h1.y;
    acc[6] += p.z * h1.z; acc[7]  += p.z * h1.w; acc[8]  += p.z * h2.x;
    acc[9] += p.w * h2.y; acc[10] += p.w * h2.z; acc[11] += p.w * h2.w;
  }
  #pragma unroll
  for (int o = 32; o; o >>= 1){
    denp.x += __shfl_xor(denp.x, o);
    denp.y += __shfl_xor(denp.y, o);
    denp.z += __shfl_xor(denp.z, o);
    denp.w += __shfl_xor(denp.w, o);
    #pragma unroll
    for (int j = 0; j < 12; j++) acc[j] += __shfl_xor(acc[j], o);
  }
  if (lane == 0){
    const float* hn = hw + (size_t)wid * 12;
    float dn[4]  = {denp.x + ps.x, denp.y + ps.y, denp.z + ps.z, denp.w + ps.w};
    float psv[4] = {ps.x, ps.y, ps.z, ps.w};
    float tot = 0.f;
    #pragma unroll
    for (int h_ = 0; h_ < 4; h_++){
      #pragma unroll
      for (int c = 0; c < 3; c++){
        float num = acc[h_ * 3 + c] + psv[h_] * hn[h_ * 3 + c];
        tot += num / dn[h_];
      }
    }
    tot = tot / 12.f + (bg2[0] + bg2[1] + bg2[2]) / 3.f;
    out[wid] = tanhf(tot);
  }
}

// ---------------- launch ----------------

extern "C" void kernel_launch(void* const* d_in, const int* in_sizes, int n_in,
                              void* d_out, int out_size, void* d_ws, size_t ws_size,
                              hipStream_t stream){
  const float* x      = (const float*)d_in[0];
  const int*   ei     = (const int*)d_in[1];
  const int*   et     = (const int*)d_in[2];
  const float* basis1 = (const float*)d_in[3];
  const float* comp1  = (const float*)d_in[4];
  const float* root1  = (const float*)d_in[5];
  const float* brg1   = (const float*)d_in[6];
  const float* Wg1    = (const float*)d_in[7];
  const float* atts1  = (const float*)d_in[8];
  const float* attd1  = (const float*)d_in[9];
  const float* bg1    = (const float*)d_in[10];
  const float* basis2 = (const float*)d_in[11];
  const float* comp2  = (const float*)d_in[12];
  const float* root2  = (const float*)d_in[13];
  const float* brg2   = (const float*)d_in[14];
  const float* Wg2    = (const float*)d_in[15];
  const float* atts2  = (const float*)d_in[16];
  const float* attd2  = (const float*)d_in[17];
  const float* bg2    = (const float*)d_in[18];
  float* out = (float*)d_out;

  const int* src = ei;
  const int* dst = ei + NE;

  char* ws = (char*)d_ws;
  size_t off = 0;
  auto alloc = [&](size_t bytes) -> void* {
    void* p = ws + off;
    off = (off + bytes + 255) & ~(size_t)255;
    return p;
  };
  // persistent
  int*   deg     = (int*)alloc((size_t)NN * 4);
  int*   cursor  = (int*)alloc((size_t)NN * 4);
  int*   offs    = (int*)alloc((size_t)(NN + 1) * 4);
  int*   bsum    = (int*)alloc((size_t)256 * 4);
  int*   csr_src = (int*)alloc((size_t)NE * 4);
  int*   csr_et  = (int*)alloc((size_t)NE * 4);
  unsigned short* Bhi2 = (unsigned short*)alloc((size_t)81920 * 2);  // L3: 20*8*64*8
  unsigned short* Blo2 = (unsigned short*)alloc((size_t)81920 * 2);
  unsigned short* Bhi1 = (unsigned short*)alloc((size_t)16384 * 2);  // GAT1: 16*2*64*8
  unsigned short* Blo1 = (unsigned short*)alloc((size_t)16384 * 2);
  float* wa_s    = (float*)alloc((size_t)256 * 4);
  float* wa_d    = (float*)alloc((size_t)256 * 4);
  float* h1      = (float*)alloc((size_t)NN * 64 * 4);
  float* h2      = (float*)alloc((size_t)NN * 256 * 4);
  float* h3      = (float*)alloc((size_t)NN * 64 * 4);
  float* hw2     = (float*)alloc((size_t)NN * 12 * 4);
  float* as1     = (float*)alloc((size_t)NN * 4 * 4);
  float* ad1     = (float*)alloc((size_t)NN * 4 * 4);
  float* as2     = (float*)alloc((size_t)NN * 4 * 4);
  float* ad2     = (float*)alloc((size_t)NN * 4 * 4);
  // scratch union S (NN*384 floats):
  //   agg1[NN*128] -> aggG[NN*256] -> { xr bf16 [NN*512] (= NN*256 floats), rootb [NN*64] }
  float* S       = (float*)alloc((size_t)NN * 384 * 4);
  float* agg1    = S;
  float* aggG    = S;
  unsigned short* xr = (unsigned short*)S;          // NN*512 ushorts = NN*256 floats
  float* rootb   = S + (size_t)NN * 256;            // NN*64 floats
  (void)ws_size; (void)n_in; (void)in_sizes; (void)out_size;

  const int BLK = 256;
  int gridN   = (NN + BLK - 1) / BLK;
  int gridE   = (NE + BLK - 1) / BLK;
  int gridW   = (NN + 3) / 4;
  int gridM64 = (NN + 63) / 64;     // 469
  int gridM256= (NN + 255) / 256;   // 118

  // CSR build + weight prep
  zero2_kernel<<<gridN, BLK, 0, stream>>>(deg, cursor, NN);
  count_kernel<<<gridE, BLK, 0, stream>>>(dst, deg, NE);
  packB2_kernel<<<(10240 + 255) / 256, BLK, 0, stream>>>(basis2, root2, Bhi2, Blo2);
  packB_kernel<<<(2048 + 255) / 256, BLK, 0, stream>>>(Wg1, 256, 2, 2048, Bhi1, Blo1);
  wa_kernel<<<1, BLK, 0, stream>>>(Wg1, atts1, attd1, wa_s, wa_d);
  scan1_kernel<<<gridN, BLK, 0, stream>>>(deg, offs, bsum);
  scan2_kernel<<<1, BLK, 0, stream>>>(bsum, gridN);
  scan3_kernel<<<gridN, BLK, 0, stream>>>(bsum, offs);
  scatter_kernel<<<gridE, BLK, 0, stream>>>(src, dst, et, offs, cursor, csr_src, csr_et, NE);

  // Layer 1: RGCN (32 -> 64) + elu, GAT1 logits fused into epilogue
  agg1_kernel<<<gridW, BLK, 0, stream>>>(x, comp1, offs, csr_src, csr_et, agg1);
  gemmT_kernel<4, true, true><<<gridM64, BLK, 0, stream>>>(
      agg1, 128, 128, basis1, 64,
      x, 32, 32, root1, 64,
      brg1, h1, 64, NN, wa_s, wa_d, as1, ad1);

  // Layer 2: GAT (64 -> 256 concat) + elu: aggregate h1 -> MFMA block-diag GEMM
  gat1_agg_kernel<<<gridW, BLK, 0, stream>>>(h1, as1, ad1, offs, csr_src, aggG);
  gemm_mfma_kernel<2, true, true><<<dim3(4, gridM256), BLK, 0, stream>>>(
      aggG, 256, 64, Bhi1, Blo1, bg1, h2, 256);

  // Layer 3: RGCN (256 -> 64) + elu: fused MFMA transform (of-split x4) -> xr + root
  gemm_l3_fused_kernel<<<dim3(4, gridM64), BLK, 0, stream>>>(h2, Bhi2, Blo2, comp2, xr, rootb);
  rgcn2_agg_kernel<<<gridW, BLK, 0, stream>>>(xr, rootb, brg2, offs, csr_src, csr_et, h3);

  // Layer 4: GAT (64 -> 4x3, mean heads) + mean classes + tanh
  gat_lin2_kernel<<<gridW, BLK, 0, stream>>>(h3, Wg2, atts2, attd2, hw2, as2, ad2);
  gat2_final_kernel<<<gridW, BLK, 0, stream>>>(hw2, as2, ad2, bg2, offs, csr_src, out);
}

// Round 19
// 274.848 us; speedup vs baseline: 1.1879x; 1.1718x over previous
//
#include <hip/hip_runtime.h>
#include <cstdint>
#include <cstddef>

#define NN 30000
#define NE 480000

typedef __attribute__((ext_vector_type(8))) short short8v;
typedef __attribute__((ext_vector_type(4))) float f32x4;

__device__ __forceinline__ float leakyf(float x){ return x > 0.f ? x : 0.2f * x; }
__device__ __forceinline__ float eluf(float x){ return x > 0.f ? x : expm1f(x); }

__device__ __forceinline__ float bf2f(unsigned short u){
  return __uint_as_float(((unsigned)u) << 16);
}
__device__ __forceinline__ unsigned short f2bf(float f){
  unsigned x = __float_as_uint(f);
  unsigned r = (x + 0x7FFFu + ((x >> 16) & 1u)) >> 16;
  return (unsigned short)r;
}

struct F4 { float x, y, z, w; };

__device__ __forceinline__ F4 ld4(const float* p){
  float4 v = *(const float4*)p;
  return F4{v.x, v.y, v.z, v.w};
}

__device__ __forceinline__ float4 redeg16(float4 v){
  v.x += __shfl_xor(v.x, 16); v.y += __shfl_xor(v.y, 16);
  v.z += __shfl_xor(v.z, 16); v.w += __shfl_xor(v.w, 16);
  v.x += __shfl_xor(v.x, 32); v.y += __shfl_xor(v.y, 32);
  v.z += __shfl_xor(v.z, 32); v.w += __shfl_xor(v.w, 32);
  return v;
}

// ---------------- CSR build ----------------

__global__ void zero2_kernel(int* __restrict__ a, int* __restrict__ b, int n){
  int i = blockIdx.x * blockDim.x + threadIdx.x;
  if (i < n){ a[i] = 0; b[i] = 0; }
}

__global__ void count_kernel(const int* __restrict__ dst, int* __restrict__ deg, int E){
  int i = blockIdx.x * blockDim.x + threadIdx.x;
  if (i < E) atomicAdd(&deg[dst[i]], 1);
}

__global__ void scan1_kernel(const int* __restrict__ deg, int* __restrict__ offs,
                             int* __restrict__ bsum){
  __shared__ int sh[256];
  int blk = blockIdx.x, t = threadIdx.x, i = blk * 256 + t;
  int v = (i < NN) ? deg[i] : 0;
  sh[t] = v; __syncthreads();
  for (int o = 1; o < 256; o <<= 1){
    int tv = (t >= o) ? sh[t - o] : 0;
    __syncthreads();
    sh[t] += tv;
    __syncthreads();
  }
  if (i < NN) offs[i + 1] = sh[t];
  if (t == 255) bsum[blk] = sh[255];
}

__global__ void scan2_kernel(int* __restrict__ bsum, int nb){
  __shared__ int sh[256];
  int t = threadIdx.x;
  int v = (t < nb) ? bsum[t] : 0;
  sh[t] = v; __syncthreads();
  for (int o = 1; o < 256; o <<= 1){
    int tv = (t >= o) ? sh[t - o] : 0;
    __syncthreads();
    sh[t] += tv;
    __syncthreads();
  }
  if (t < nb) bsum[t] = sh[t];
}

__global__ void scan3_kernel(const int* __restrict__ bsum, int* __restrict__ offs){
  int i = blockIdx.x * 256 + threadIdx.x;
  if (i == 0) offs[0] = 0;
  if (i < NN){
    int blk = i >> 8;
    int add = blk ? bsum[blk - 1] : 0;
    offs[i + 1] += add;
  }
}

__global__ void scatter_kernel(const int* __restrict__ src, const int* __restrict__ dst,
                               const int* __restrict__ et, const int* __restrict__ offs,
                               int* __restrict__ cursor, int* __restrict__ csr_src,
                               int* __restrict__ csr_et, int E){
  int i = blockIdx.x * blockDim.x + threadIdx.x;
  if (i < E){
    int d = dst[i];
    int pos = offs[d] + atomicAdd(&cursor[d], 1);
    csr_src[pos] = src[i];
    csr_et[pos]  = et[i];
  }
}

// ---------------- weight prep ----------------

// L3 B-fragments straight from basis2/root2 (virtual Wcat cols: 0..255 basis, 256..319 root).
__global__ void packB2_kernel(const float* __restrict__ basis2, const float* __restrict__ root2,
                              unsigned short* __restrict__ Bhi, unsigned short* __restrict__ Blo){
  int idx = blockIdx.x * 256 + threadIdx.x;
  if (idx >= 10240) return;
  int lane = idx & 63;
  int rest = idx >> 6;
  int ks = rest & 7;
  int nf16 = rest >> 3;                       // 0..19
  int col = nf16 * 16 + (lane & 15);
  int kbase = ks * 32 + ((lane >> 4) << 3);
  size_t obase = (size_t)idx * 8;
  #pragma unroll
  for (int j = 0; j < 8; j++){
    int k = kbase + j;
    float v;
    if (col < 256){
      int b = col >> 6, c = col & 63;
      v = basis2[((size_t)b * 256 + k) * 64 + c];
    } else {
      v = root2[(size_t)k * 64 + (col - 256)];
    }
    unsigned short h = f2bf(v);
    float res = v - bf2f(h);
    Bhi[obase + j] = h;
    Blo[obase + j] = f2bf(res);
  }
}

// generic MFMA B-fragment pack (GAT1 Wg1), bf16 hi/lo split.
__global__ void packB_kernel(const float* __restrict__ W, int ldw, int ksteps, int total,
                             unsigned short* __restrict__ Bhi, unsigned short* __restrict__ Blo){
  int idx = blockIdx.x * 256 + threadIdx.x;
  if (idx >= total) return;
  int lane = idx & 63;
  int rest = idx >> 6;
  int ks = rest % ksteps;
  int nf16 = rest / ksteps;
  int col = nf16 * 16 + (lane & 15);
  int kbase = ks * 32 + ((lane >> 4) << 3);
  size_t obase = (size_t)idx * 8;
  #pragma unroll
  for (int j = 0; j < 8; j++){
    float v = W[(size_t)(kbase + j) * ldw + col];
    unsigned short h = f2bf(v);
    float res = v - bf2f(h);
    Bhi[obase + j] = h;
    Blo[obase + j] = f2bf(res);
  }
}

// wa_s[k*4+h] = sum_c Wg1[k, h*64+c] * atts1[h,c]  (and wa_d with attd1)
__global__ void wa_kernel(const float* __restrict__ Wg1, const float* __restrict__ atts1,
                          const float* __restrict__ attd1, float* __restrict__ wa_s,
                          float* __restrict__ wa_d){
  int t = threadIdx.x;
  int k = t >> 2, h = t & 3;
  float s = 0.f, d = 0.f;
  const float* wr = Wg1 + (size_t)k * 256 + h * 64;
  const float* pa = atts1 + h * 64;
  const float* pb = attd1 + h * 64;
  #pragma unroll 8
  for (int c = 0; c < 64; c++){ s += wr[c] * pa[c]; d += wr[c] * pb[c]; }
  wa_s[k * 4 + h] = s;
  wa_d[k * 4 + h] = d;
}

// ---------------- layer-1 basis-space aggregation (4 edge-groups x float2) ----------------

__global__ void agg1_kernel(const float* __restrict__ x, const float* __restrict__ comp,
                            const int* __restrict__ offs, const int* __restrict__ csr_src,
                            const int* __restrict__ csr_et, float* __restrict__ agg){
  int wid  = (blockIdx.x * blockDim.x + threadIdx.x) >> 6;
  int lane = threadIdx.x & 63;
  if (wid >= NN) return;
  int q = lane & 15, eg = lane >> 4;
  int c2 = q * 2;
  int n0 = offs[wid], n1 = offs[wid + 1];
  float a00 = 0.f, a01 = 0.f, a10 = 0.f, a11 = 0.f;
  float a20 = 0.f, a21 = 0.f, a30 = 0.f, a31 = 0.f;
  for (int k = n0 + eg; k < n1; k += 4){
    int s = csr_src[k], e = csr_et[k];
    float2 v = *(const float2*)(x + (size_t)s * 32 + c2);
    F4 cp = ld4(comp + (size_t)e * 4);
    a00 += cp.x * v.x; a01 += cp.x * v.y;
    a10 += cp.y * v.x; a11 += cp.y * v.y;
    a20 += cp.z * v.x; a21 += cp.z * v.y;
    a30 += cp.w * v.x; a31 += cp.w * v.y;
  }
  #pragma unroll
  for (int o = 16; o < 64; o <<= 1){
    a00 += __shfl_xor(a00, o); a01 += __shfl_xor(a01, o);
    a10 += __shfl_xor(a10, o); a11 += __shfl_xor(a11, o);
    a20 += __shfl_xor(a20, o); a21 += __shfl_xor(a21, o);
    a30 += __shfl_xor(a30, o); a31 += __shfl_xor(a31, o);
  }
  int dg = n1 - n0;
  float sc = 1.f / (float)(dg > 0 ? dg : 1);
  if (lane < 16){
    float* ar = agg + (size_t)wid * 128 + c2;
    *(float2*)(ar)      = make_float2(a00 * sc, a01 * sc);
    *(float2*)(ar + 32) = make_float2(a10 * sc, a11 * sc);
    *(float2*)(ar + 64) = make_float2(a20 * sc, a21 * sc);
    *(float2*)(ar + 96) = make_float2(a30 * sc, a31 * sc);
  }
}

// ---------------- (RPT*16)-row x 64-col fused GEMM (layer 1), logits fused ----------------

template<int RPT, bool ELU, bool LOGITS>
__global__ __launch_bounds__(256) void gemmT_kernel(
    const float* __restrict__ A1, int lda1, int K1,
    const float* __restrict__ W1, int ldw1,
    const float* __restrict__ A2, int lda2, int K2,
    const float* __restrict__ W2, int ldw2,
    const float* __restrict__ bias,
    float* __restrict__ Y, int ldy,
    int nrows,
    const float* __restrict__ wa_s, const float* __restrict__ wa_d,
    float* __restrict__ as_, float* __restrict__ ad_)
{
  __shared__ float At[32][RPT * 16 + 4];
  __shared__ float Wl[32][68];
  int t = threadIdx.x;
  int tc = t & 15, tr = t >> 4;
  int nbase = blockIdx.x * (RPT * 16);
  float acc[RPT][4];
  #pragma unroll
  for (int j = 0; j < RPT; j++)
    #pragma unroll
    for (int i = 0; i < 4; i++) acc[j][i] = 0.f;

  for (int seg = 0; seg < 2; seg++){
    const float* A = seg ? A2 : A1;
    const float* W = seg ? W2 : W1;
    int lda = seg ? lda2 : lda1;
    int ldw = seg ? ldw2 : ldw1;
    int K   = seg ? K2 : K1;
    if (A == nullptr || K <= 0) continue;
    for (int k0 = 0; k0 < K; k0 += 32){
      #pragma unroll
      for (int i = 0; i < 2; i++){
        int e = i * 256 + t;
        int kk = e >> 4, c4 = (e & 15) << 2;
        float4 v = make_float4(0.f, 0.f, 0.f, 0.f);
        if (k0 + kk < K) v = *(const float4*)(W + (size_t)(k0 + kk) * ldw + c4);
        *(float4*)&Wl[kk][c4] = v;
      }
      #pragma unroll
      for (int i = 0; i < RPT / 2; i++){
        int e = i * 256 + t;
        int r = e >> 3, c4 = (e & 7) << 2;
        int n = nbase + r;
        float4 v = make_float4(0.f, 0.f, 0.f, 0.f);
        if (n < nrows && k0 + c4 < K) v = *(const float4*)(A + (size_t)n * lda + k0 + c4);
        At[c4 + 0][r] = v.x;
        At[c4 + 1][r] = v.y;
        At[c4 + 2][r] = v.z;
        At[c4 + 3][r] = v.w;
      }
      __syncthreads();
      #pragma unroll 4
      for (int k = 0; k < 32; k++){
        float4 wv = *(const float4*)&Wl[k][tc * 4];
        const float* pw = (const float*)&wv;
        #pragma unroll
        for (int jj = 0; jj < RPT / 4; jj++){
          float4 av = *(const float4*)&At[k][tr * RPT + jj * 4];
          const float* pa = (const float*)&av;
          #pragma unroll
          for (int j = 0; j < 4; j++)
            #pragma unroll
            for (int i = 0; i < 4; i++)
              acc[jj * 4 + j][i] = fmaf(pa[j], pw[i], acc[jj * 4 + j][i]);
        }
      }
      __syncthreads();
    }
  }

  float b0 = bias[tc * 4 + 0], b1 = bias[tc * 4 + 1];
  float b2 = bias[tc * 4 + 2], b3 = bias[tc * 4 + 3];
  float4 ws0, ws1, ws2, ws3, wd0, wd1, wd2, wd3;
  if (LOGITS){
    ws0 = *(const float4*)(wa_s + (tc*4+0)*4); wd0 = *(const float4*)(wa_d + (tc*4+0)*4);
    ws1 = *(const float4*)(wa_s + (tc*4+1)*4); wd1 = *(const float4*)(wa_d + (tc*4+1)*4);
    ws2 = *(const float4*)(wa_s + (tc*4+2)*4); wd2 = *(const float4*)(wa_d + (tc*4+2)*4);
    ws3 = *(const float4*)(wa_s + (tc*4+3)*4); wd3 = *(const float4*)(wa_d + (tc*4+3)*4);
  }
  #pragma unroll
  for (int j = 0; j < RPT; j++){
    int n = nbase + tr * RPT + j;
    float y0 = acc[j][0] + b0, y1 = acc[j][1] + b1;
    float y2 = acc[j][2] + b2, y3 = acc[j][3] + b3;
    if (ELU){ y0 = eluf(y0); y1 = eluf(y1); y2 = eluf(y2); y3 = eluf(y3); }
    if (n < nrows)
      *(float4*)(Y + (size_t)n * ldy + tc * 4) = make_float4(y0, y1, y2, y3);
    if (LOGITS){
      float s0 = y0*ws0.x + y1*ws1.x + y2*ws2.x + y3*ws3.x;
      float s1 = y0*ws0.y + y1*ws1.y + y2*ws2.y + y3*ws3.y;
      float s2 = y0*ws0.z + y1*ws1.z + y2*ws2.z + y3*ws3.z;
      float s3 = y0*ws0.w + y1*ws1.w + y2*ws2.w + y3*ws3.w;
      float d0 = y0*wd0.x + y1*wd1.x + y2*wd2.x + y3*wd3.x;
      float d1 = y0*wd0.y + y1*wd1.y + y2*wd2.y + y3*wd3.y;
      float d2 = y0*wd0.z + y1*wd1.z + y2*wd2.z + y3*wd3.z;
      float d3 = y0*wd0.w + y1*wd1.w + y2*wd2.w + y3*wd3.w;
      #pragma unroll
      for (int o = 1; o < 16; o <<= 1){
        s0 += __shfl_xor(s0, o); s1 += __shfl_xor(s1, o);
        s2 += __shfl_xor(s2, o); s3 += __shfl_xor(s3, o);
        d0 += __shfl_xor(d0, o); d1 += __shfl_xor(d1, o);
        d2 += __shfl_xor(d2, o); d3 += __shfl_xor(d3, o);
      }
      if (tc == 0 && n < nrows){
        *(float4*)(as_ + n * 4) = make_float4(s0, s1, s2, s3);
        *(float4*)(ad_ + n * 4) = make_float4(d0, d1, d2, d3);
      }
    }
  }
}

// ---------------- generic bf16-split MFMA GEMM (GAT1 block-diag) ----------------

template<int KSTEPS, bool ELU, bool BIAS>
__global__ __launch_bounds__(256) void gemm_mfma_kernel(
    const float* __restrict__ A, int lda, int acgoff,
    const unsigned short* __restrict__ Bhi, const unsigned short* __restrict__ Blo,
    const float* __restrict__ bias, float* __restrict__ Y, int ldy)
{
  int t = threadIdx.x;
  int lane = t & 63, wv = t >> 6;
  int cg = blockIdx.x;
  int mbase = blockIdx.y * 256 + wv * 64;
  int fr = lane & 15;
  int ksub = (lane >> 4) << 3;
  const float* Ab = A + (size_t)cg * acgoff;
  f32x4 acc[4][4];
  #pragma unroll
  for (int mi = 0; mi < 4; mi++)
    #pragma unroll
    for (int ni = 0; ni < 4; ni++)
      acc[mi][ni] = (f32x4){0.f, 0.f, 0.f, 0.f};

  #pragma unroll
  for (int ks = 0; ks < KSTEPS; ks++){
    short8v ahi[4], alo[4];
    #pragma unroll
    for (int mi = 0; mi < 4; mi++){
      int r = mbase + mi * 16 + fr;
      float av[8];
      if (r < NN){
        float4 p0 = *(const float4*)(Ab + (size_t)r * lda + ks * 32 + ksub);
        float4 p1 = *(const float4*)(Ab + (size_t)r * lda + ks * 32 + ksub + 4);
        av[0] = p0.x; av[1] = p0.y; av[2] = p0.z; av[3] = p0.w;
        av[4] = p1.x; av[5] = p1.y; av[6] = p1.z; av[7] = p1.w;
      } else {
        #pragma unroll
        for (int j = 0; j < 8; j++) av[j] = 0.f;
      }
      #pragma unroll
      for (int j = 0; j < 8; j++){
        unsigned short h = f2bf(av[j]);
        float res = av[j] - bf2f(h);
        ahi[mi][j] = (short)h;
        alo[mi][j] = (short)f2bf(res);
      }
    }
    #pragma unroll
    for (int ni = 0; ni < 4; ni++){
      size_t boff = ((((size_t)(cg * 4 + ni)) * KSTEPS + ks) * 64 + lane) * 8;
      short8v bh = *(const short8v*)(Bhi + boff);
      short8v bl = *(const short8v*)(Blo + boff);
      #pragma unroll
      for (int mi = 0; mi < 4; mi++){
        acc[mi][ni] = __builtin_amdgcn_mfma_f32_16x16x32_bf16(ahi[mi], bh, acc[mi][ni], 0, 0, 0);
        acc[mi][ni] = __builtin_amdgcn_mfma_f32_16x16x32_bf16(ahi[mi], bl, acc[mi][ni], 0, 0, 0);
        acc[mi][ni] = __builtin_amdgcn_mfma_f32_16x16x32_bf16(alo[mi], bh, acc[mi][ni], 0, 0, 0);
      }
    }
  }
  int crow = (lane >> 4) << 2;
  #pragma unroll
  for (int mi = 0; mi < 4; mi++){
    #pragma unroll
    for (int reg = 0; reg < 4; reg++){
      int r = mbase + mi * 16 + crow + reg;
      if (r < NN){
        #pragma unroll
        for (int ni = 0; ni < 4; ni++){
          float y = acc[mi][ni][reg];
          if (BIAS) y += bias[cg * 64 + ni * 16 + fr];
          if (ELU)  y = eluf(y);
          Y[(size_t)r * ldy + cg * 64 + ni * 16 + fr] = y;
        }
      }
    }
  }
}

// ---------------- L3 fused MFMA GEMM, 4-way of-split (measured best) ----------------

__global__ __launch_bounds__(256) void gemm_l3_fused_kernel(
    const float* __restrict__ A,
    const unsigned short* __restrict__ Bhi, const unsigned short* __restrict__ Blo,
    const float* __restrict__ comp2,
    unsigned short* __restrict__ xr, float* __restrict__ rootb)
{
  int t = threadIdx.x;
  int lane = t & 63, wv = t >> 6;
  int of = blockIdx.x;
  int mbase = blockIdx.y * 64 + wv * 16;
  int fr = lane & 15;
  int ksub = (lane >> 4) << 3;
  f32x4 acc[5];
  #pragma unroll
  for (int b = 0; b < 5; b++) acc[b] = (f32x4){0.f, 0.f, 0.f, 0.f};

  int ar = mbase + fr;
  bool arok = (ar < NN);
  for (int ks = 0; ks < 8; ks++){
    float av[8];
    if (arok){
      float4 p0 = *(const float4*)(A + (size_t)ar * 256 + ks * 32 + ksub);
      float4 p1 = *(const float4*)(A + (size_t)ar * 256 + ks * 32 + ksub + 4);
      av[0] = p0.x; av[1] = p0.y; av[2] = p0.z; av[3] = p0.w;
      av[4] = p1.x; av[5] = p1.y; av[6] = p1.z; av[7] = p1.w;
    } else {
      #pragma unroll
      for (int j = 0; j < 8; j++) av[j] = 0.f;
    }
    short8v ahi, alo;
    #pragma unroll
    for (int j = 0; j < 8; j++){
      unsigned short h = f2bf(av[j]);
      float res = av[j] - bf2f(h);
      ahi[j] = (short)h;
      alo[j] = (short)f2bf(res);
    }
    #pragma unroll
    for (int b = 0; b < 5; b++){
      int nig = b * 4 + of;                 // b<4: basis, b=4: root
      size_t boff = (((size_t)nig * 8 + ks) * 64 + lane) * 8;
      short8v bh = *(const short8v*)(Bhi + boff);
      short8v bl = *(const short8v*)(Blo + boff);
      acc[b] = __builtin_amdgcn_mfma_f32_16x16x32_bf16(ahi, bh, acc[b], 0, 0, 0);
      acc[b] = __builtin_amdgcn_mfma_f32_16x16x32_bf16(ahi, bl, acc[b], 0, 0, 0);
      acc[b] = __builtin_amdgcn_mfma_f32_16x16x32_bf16(alo, bh, acc[b], 0, 0, 0);
    }
  }

  float cp[32];
  #pragma unroll
  for (int i = 0; i < 32; i++) cp[i] = comp2[i];
  int crow = (lane >> 4) << 2;
  int col = of * 16 + fr;
  #pragma unroll
  for (int reg = 0; reg < 4; reg++){
    int r = mbase + crow + reg;
    if (r >= NN) continue;
    float b0 = acc[0][reg], b1 = acc[1][reg], b2 = acc[2][reg], b3 = acc[3][reg];
    rootb[(size_t)r * 64 + col] = acc[4][reg];
    #pragma unroll
    for (int rr = 0; rr < 8; rr++){
      float m = cp[rr*4+0]*b0 + cp[rr*4+1]*b1 + cp[rr*4+2]*b2 + cp[rr*4+3]*b3;
      xr[((size_t)r * 8 + rr) * 64 + col] = f2bf(m);
    }
  }
}

// ---------------- GAT1 aggregate: 4 edge-groups x 16 ch-lanes, 4 heads per lane ----------------

__global__ void gat1_agg_kernel(const float* __restrict__ h1, const float* __restrict__ as_,
                                const float* __restrict__ ad_, const int* __restrict__ offs,
                                const int* __restrict__ csr_src, float* __restrict__ aggG){
  int wid  = (blockIdx.x * blockDim.x + threadIdx.x) >> 6;
  int lane = threadIdx.x & 63;
  if (wid >= NN) return;
  int n0 = offs[wid], n1 = offs[wid + 1];
  int h = lane & 3;
  float adn_s = ad_[wid * 4 + h];
  float m = leakyf(as_[wid * 4 + h] + adn_s);
  for (int k = n0 + (lane >> 2); k < n1; k += 16){
    int s = csr_src[k];
    m = fmaxf(m, leakyf(as_[s * 4 + h] + adn_s));
  }
  #pragma unroll
  for (int o = 4; o < 64; o <<= 1) m = fmaxf(m, __shfl_xor(m, o));
  float m0 = __shfl(m, 0), m1 = __shfl(m, 1), m2 = __shfl(m, 2), m3 = __shfl(m, 3);
  int q = lane & 15, eg = lane >> 4;
  F4 adn = ld4(ad_ + (size_t)wid * 4);
  float den0 = 0.f, den1 = 0.f, den2 = 0.f, den3 = 0.f;
  float4 ac0 = make_float4(0.f,0.f,0.f,0.f), ac1 = ac0, ac2 = ac0, ac3 = ac0;
  for (int k = n0 + eg; k < n1; k += 4){
    int s = csr_src[k];
    F4 a = ld4(as_ + (size_t)s * 4);
    float p0 = expf(leakyf(a.x + adn.x) - m0);
    float p1 = expf(leakyf(a.y + adn.y) - m1);
    float p2 = expf(leakyf(a.z + adn.z) - m2);
    float p3 = expf(leakyf(a.w + adn.w) - m3);
    den0 += p0; den1 += p1; den2 += p2; den3 += p3;
    float4 v = *(const float4*)(h1 + (size_t)s * 64 + q * 4);
    ac0.x += p0*v.x; ac0.y += p0*v.y; ac0.z += p0*v.z; ac0.w += p0*v.w;
    ac1.x += p1*v.x; ac1.y += p1*v.y; ac1.z += p1*v.z; ac1.w += p1*v.w;
    ac2.x += p2*v.x; ac2.y += p2*v.y; ac2.z += p2*v.z; ac2.w += p2*v.w;
    ac3.x += p3*v.x; ac3.y += p3*v.y; ac3.z += p3*v.z; ac3.w += p3*v.w;
  }
  #pragma unroll
  for (int o = 16; o < 64; o <<= 1){
    den0 += __shfl_xor(den0, o); den1 += __shfl_xor(den1, o);
    den2 += __shfl_xor(den2, o); den3 += __shfl_xor(den3, o);
  }
  ac0 = redeg16(ac0); ac1 = redeg16(ac1); ac2 = redeg16(ac2); ac3 = redeg16(ac3);
  F4 asn = ld4(as_ + (size_t)wid * 4);
  float ps0 = expf(leakyf(asn.x + adn.x) - m0);
  float ps1 = expf(leakyf(asn.y + adn.y) - m1);
  float ps2 = expf(leakyf(asn.z + adn.z) - m2);
  float ps3 = expf(leakyf(asn.w + adn.w) - m3);
  if (lane < 16){
    float4 v = *(const float4*)(h1 + (size_t)wid * 64 + q * 4);
    float i0 = 1.f / (den0 + ps0), i1 = 1.f / (den1 + ps1);
    float i2 = 1.f / (den2 + ps2), i3 = 1.f / (den3 + ps3);
    float* ag = aggG + (size_t)wid * 256 + q * 4;
    *(float4*)(ag)       = make_float4((ac0.x+ps0*v.x)*i0, (ac0.y+ps0*v.y)*i0, (ac0.z+ps0*v.z)*i0, (ac0.w+ps0*v.w)*i0);
    *(float4*)(ag + 64)  = make_float4((ac1.x+ps1*v.x)*i1, (ac1.y+ps1*v.y)*i1, (ac1.z+ps1*v.z)*i1, (ac1.w+ps1*v.w)*i1);
    *(float4*)(ag + 128) = make_float4((ac2.x+ps2*v.x)*i2, (ac2.y+ps2*v.y)*i2, (ac2.z+ps2*v.z)*i2, (ac2.w+ps2*v.w)*i2);
    *(float4*)(ag + 192) = make_float4((ac3.x+ps3*v.x)*i3, (ac3.y+ps3*v.y)*i3, (ac3.z+ps3*v.z)*i3, (ac3.w+ps3*v.w)*i3);
  }
}

// ---------------- layer-3 aggregate: 8 edge-groups x 8 ch-lanes (ushort8 gathers) ----------

__global__ void rgcn2_agg_kernel(const unsigned short* __restrict__ xr,
                                 const float* __restrict__ rootb,
                                 const float* __restrict__ bias, const int* __restrict__ offs,
                                 const int* __restrict__ csr_src, const int* __restrict__ csr_et,
                                 float* __restrict__ h3){
  int wid  = (blockIdx.x * blockDim.x + threadIdx.x) >> 6;
  int lane = threadIdx.x & 63;
  if (wid >= NN) return;
  int q = lane & 7, eg = lane >> 3;
  int n0 = offs[wid], n1 = offs[wid + 1];
  float a[8];
  #pragma unroll
  for (int j = 0; j < 8; j++) a[j] = 0.f;
  for (int k = n0 + eg; k < n1; k += 8){
    int s = csr_src[k], e = csr_et[k];
    short8v u = *(const short8v*)(xr + ((size_t)s * 8 + e) * 64 + q * 8);
    #pragma unroll
    for (int j = 0; j < 8; j++) a[j] += bf2f((unsigned short)u[j]);
  }
  #pragma unroll
  for (int o = 8; o < 64; o <<= 1){
    #pragma unroll
    for (int j = 0; j < 8; j++) a[j] += __shfl_xor(a[j], o);
  }
  int dg = n1 - n0;
  float sc = 1.f / (float)(dg > 0 ? dg : 1);
  if (lane < 8){
    const float* rb = rootb + (size_t)wid * 64 + q * 8;
    float4 r0 = *(const float4*)(rb);
    float4 r1 = *(const float4*)(rb + 4);
    float4 b0 = *(const float4*)(bias + q * 8);
    float4 b1 = *(const float4*)(bias + q * 8 + 4);
    float* hp = h3 + (size_t)wid * 64 + q * 8;
    *(float4*)(hp)     = make_float4(eluf(a[0]*sc + r0.x + b0.x), eluf(a[1]*sc + r0.y + b0.y),
                                     eluf(a[2]*sc + r0.z + b0.z), eluf(a[3]*sc + r0.w + b0.w));
    *(float4*)(hp + 4) = make_float4(eluf(a[4]*sc + r1.x + b1.x), eluf(a[5]*sc + r1.y + b1.y),
                                     eluf(a[6]*sc + r1.z + b1.z), eluf(a[7]*sc + r1.w + b1.w));
  }
}

// ---------------- GAT2: linear (4 nodes/wave, 16 lanes/node) ----------------

__global__ void gat_lin2_kernel(const float* __restrict__ h, const float* __restrict__ W,
                                const float* __restrict__ atts, const float* __restrict__ attd,
                                float* __restrict__ hw, float* __restrict__ as_, float* __restrict__ ad_){
  __shared__ float Wl[64][13];
  __shared__ float sa[12], sd[12];
  int t = threadIdx.x;
  for (int i = t; i < 768; i += 256) Wl[i / 12][i % 12] = W[i];
  if (t < 12){ sa[t] = atts[t]; sd[t] = attd[t]; }
  __syncthreads();
  int idx = blockIdx.x * 256 + t;
  int n = idx >> 4, c = idx & 15;
  if (n >= NN) return;
  float acc = 0.f;
  if (c < 12){
    const float* hr = h + (size_t)n * 64;
    #pragma unroll 8
    for (int i = 0; i < 64; i++) acc += hr[i] * Wl[i][c];
    hw[(size_t)n * 12 + c] = acc;
  }
  float ts = (c < 12) ? acc * sa[c] : 0.f;
  float td = (c < 12) ? acc * sd[c] : 0.f;
  int lane = t & 63;
  int base = lane & 48;                       // 16-lane group base
  int b = base + ((c < 4) ? c * 3 : 0);
  float s0 = __shfl(ts, b) + __shfl(ts, b + 1) + __shfl(ts, b + 2);
  float d0 = __shfl(td, b) + __shfl(td, b + 1) + __shfl(td, b + 2);
  if (c < 4){ as_[n * 4 + c] = s0; ad_[n * 4 + c] = d0; }
}

// ---------------- GAT2 final: 4 nodes/wave, 16 edge-lanes/node ----------------

__global__ void gat2_final_kernel(const float* __restrict__ hw, const float* __restrict__ as_,
                                  const float* __restrict__ ad_, const float* __restrict__ bg2,
                                  const int* __restrict__ offs, const int* __restrict__ csr_src,
                                  float* __restrict__ out){
  int gwid = (blockIdx.x * blockDim.x + threadIdx.x) >> 6;  // wave id
  int lane = threadIdx.x & 63;
  int g = lane >> 4, e = lane & 15;
  int node = gwid * 4 + g;
  if (node >= NN) return;
  int n0 = offs[node], n1 = offs[node + 1];
  F4 adn = ld4(ad_ + (size_t)node * 4);
  F4 asn = ld4(as_ + (size_t)node * 4);
  F4 es{leakyf(asn.x + adn.x), leakyf(asn.y + adn.y), leakyf(asn.z + adn.z), leakyf(asn.w + adn.w)};
  F4 m = es;
  for (int k = n0 + e; k < n1; k += 16){
    int s = csr_src[k];
    F4 a = ld4(as_ + (size_t)s * 4);
    m.x = fmaxf(m.x, leakyf(a.x + adn.x));
    m.y = fmaxf(m.y, leakyf(a.y + adn.y));
    m.z = fmaxf(m.z, leakyf(a.z + adn.z));
    m.w = fmaxf(m.w, leakyf(a.w + adn.w));
  }
  #pragma unroll
  for (int o = 1; o < 16; o <<= 1){
    m.x = fmaxf(m.x, __shfl_xor(m.x, o));
    m.y = fmaxf(m.y, __shfl_xor(m.y, o));
    m.z = fmaxf(m.z, __shfl_xor(m.z, o));
    m.w = fmaxf(m.w, __shfl_xor(m.w, o));
  }
  F4 ps{expf(es.x - m.x), expf(es.y - m.y), expf(es.z - m.z), expf(es.w - m.w)};
  float acc[12];
  #pragma unroll
  for (int j = 0; j < 12; j++) acc[j] = 0.f;
  F4 denp{0.f, 0.f, 0.f, 0.f};
  for (int k = n0 + e; k < n1; k += 16){
    int s = csr_src[k];
    F4 a = ld4(as_ + (size_t)s * 4);
    F4 p{expf(leakyf(a.x + adn.x) - m.x), expf(leakyf(a.y + adn.y) - m.y),
         expf(leakyf(a.z + adn.z) - m.z), expf(leakyf(a.w + adn.w) - m.w)};
    denp.x += p.x; denp.y += p.y; denp.z += p.z; denp.w += p.w;
    const float* hb = hw + (size_t)s * 12;
    F4 h0 = ld4(hb), h1 = ld4(hb + 4), h2 = ld4(hb + 8);
    acc[0] += p.x * h0.x; acc[1]  += p.x * h0.y; acc[2]  += p.x * h0.z;
    acc[3] += p.y * h0.w; acc[4]  += p.y * h1.x; acc[5]  += p.y * h1.y;
    acc[6] += p.z * h1.z; acc[7]  += p.z * h1.w; acc[8]  += p.z * h2.x;
    acc[9] += p.w * h2.y; acc[10] += p.w * h2.z; acc[11] += p.w * h2.w;
  }
  #pragma unroll
  for (int o = 1; o < 16; o <<= 1){
    denp.x += __shfl_xor(denp.x, o);
    denp.y += __shfl_xor(denp.y, o);
    denp.z += __shfl_xor(denp.z, o);
    denp.w += __shfl_xor(denp.w, o);
    #pragma unroll
    for (int j = 0; j < 12; j++) acc[j] += __shfl_xor(acc[j], o);
  }
  if (e == 0){
    const float* hn = hw + (size_t)node * 12;
    float dn[4]  = {denp.x + ps.x, denp.y + ps.y, denp.z + ps.z, denp.w + ps.w};
    float psv[4] = {ps.x, ps.y, ps.z, ps.w};
    float tot = 0.f;
    #pragma unroll
    for (int h_ = 0; h_ < 4; h_++){
      #pragma unroll
      for (int c = 0; c < 3; c++){
        float num = acc[h_ * 3 + c] + psv[h_] * hn[h_ * 3 + c];
        tot += num / dn[h_];
      }
    }
    tot = tot / 12.f + (bg2[0] + bg2[1] + bg2[2]) / 3.f;
    out[node] = tanhf(tot);
  }
}

// ---------------- launch ----------------

extern "C" void kernel_launch(void* const* d_in, const int* in_sizes, int n_in,
                              void* d_out, int out_size, void* d_ws, size_t ws_size,
                              hipStream_t stream){
  const float* x      = (const float*)d_in[0];
  const int*   ei     = (const int*)d_in[1];
  const int*   et     = (const int*)d_in[2];
  const float* basis1 = (const float*)d_in[3];
  const float* comp1  = (const float*)d_in[4];
  const float* root1  = (const float*)d_in[5];
  const float* brg1   = (const float*)d_in[6];
  const float* Wg1    = (const float*)d_in[7];
  const float* atts1  = (const float*)d_in[8];
  const float* attd1  = (const float*)d_in[9];
  const float* bg1    = (const float*)d_in[10];
  const float* basis2 = (const float*)d_in[11];
  const float* comp2  = (const float*)d_in[12];
  const float* root2  = (const float*)d_in[13];
  const float* brg2   = (const float*)d_in[14];
  const float* Wg2    = (const float*)d_in[15];
  const float* atts2  = (const float*)d_in[16];
  const float* attd2  = (const float*)d_in[17];
  const float* bg2    = (const float*)d_in[18];
  float* out = (float*)d_out;

  const int* src = ei;
  const int* dst = ei + NE;

  char* ws = (char*)d_ws;
  size_t off = 0;
  auto alloc = [&](size_t bytes) -> void* {
    void* p = ws + off;
    off = (off + bytes + 255) & ~(size_t)255;
    return p;
  };
  // persistent
  int*   deg     = (int*)alloc((size_t)NN * 4);
  int*   cursor  = (int*)alloc((size_t)NN * 4);
  int*   offs    = (int*)alloc((size_t)(NN + 1) * 4);
  int*   bsum    = (int*)alloc((size_t)256 * 4);
  int*   csr_src = (int*)alloc((size_t)NE * 4);
  int*   csr_et  = (int*)alloc((size_t)NE * 4);
  unsigned short* Bhi2 = (unsigned short*)alloc((size_t)81920 * 2);  // L3: 20*8*64*8
  unsigned short* Blo2 = (unsigned short*)alloc((size_t)81920 * 2);
  unsigned short* Bhi1 = (unsigned short*)alloc((size_t)16384 * 2);  // GAT1: 16*2*64*8
  unsigned short* Blo1 = (unsigned short*)alloc((size_t)16384 * 2);
  float* wa_s    = (float*)alloc((size_t)256 * 4);
  float* wa_d    = (float*)alloc((size_t)256 * 4);
  float* h1      = (float*)alloc((size_t)NN * 64 * 4);
  float* h2      = (float*)alloc((size_t)NN * 256 * 4);
  float* h3      = (float*)alloc((size_t)NN * 64 * 4);
  float* hw2     = (float*)alloc((size_t)NN * 12 * 4);
  float* as1     = (float*)alloc((size_t)NN * 4 * 4);
  float* ad1     = (float*)alloc((size_t)NN * 4 * 4);
  float* as2     = (float*)alloc((size_t)NN * 4 * 4);
  float* ad2     = (float*)alloc((size_t)NN * 4 * 4);
  // scratch union S (NN*384 floats):
  //   agg1[NN*128] -> aggG[NN*256] -> { xr bf16 [NN*512] (= NN*256 floats), rootb [NN*64] }
  float* S       = (float*)alloc((size_t)NN * 384 * 4);
  float* agg1    = S;
  float* aggG    = S;
  unsigned short* xr = (unsigned short*)S;          // NN*512 ushorts = NN*256 floats
  float* rootb   = S + (size_t)NN * 256;            // NN*64 floats
  (void)ws_size; (void)n_in; (void)in_sizes; (void)out_size;

  const int BLK = 256;
  int gridN   = (NN + BLK - 1) / BLK;
  int gridE   = (NE + BLK - 1) / BLK;
  int gridW   = (NN + 3) / 4;       // 1 node/wave kernels
  int gridW4  = (NN + 15) / 16;     // 4 nodes/wave kernels
  int gridM64 = (NN + 63) / 64;     // 469
  int gridM256= (NN + 255) / 256;   // 118

  // CSR build + weight prep
  zero2_kernel<<<gridN, BLK, 0, stream>>>(deg, cursor, NN);
  count_kernel<<<gridE, BLK, 0, stream>>>(dst, deg, NE);
  packB2_kernel<<<(10240 + 255) / 256, BLK, 0, stream>>>(basis2, root2, Bhi2, Blo2);
  packB_kernel<<<(2048 + 255) / 256, BLK, 0, stream>>>(Wg1, 256, 2, 2048, Bhi1, Blo1);
  wa_kernel<<<1, BLK, 0, stream>>>(Wg1, atts1, attd1, wa_s, wa_d);
  scan1_kernel<<<gridN, BLK, 0, stream>>>(deg, offs, bsum);
  scan2_kernel<<<1, BLK, 0, stream>>>(bsum, gridN);
  scan3_kernel<<<gridN, BLK, 0, stream>>>(bsum, offs);
  scatter_kernel<<<gridE, BLK, 0, stream>>>(src, dst, et, offs, cursor, csr_src, csr_et, NE);

  // Layer 1: RGCN (32 -> 64) + elu, GAT1 logits fused into epilogue
  agg1_kernel<<<gridW, BLK, 0, stream>>>(x, comp1, offs, csr_src, csr_et, agg1);
  gemmT_kernel<4, true, true><<<gridM64, BLK, 0, stream>>>(
      agg1, 128, 128, basis1, 64,
      x, 32, 32, root1, 64,
      brg1, h1, 64, NN, wa_s, wa_d, as1, ad1);

  // Layer 2: GAT (64 -> 256 concat) + elu: aggregate h1 -> MFMA block-diag GEMM
  gat1_agg_kernel<<<gridW, BLK, 0, stream>>>(h1, as1, ad1, offs, csr_src, aggG);
  gemm_mfma_kernel<2, true, true><<<dim3(4, gridM256), BLK, 0, stream>>>(
      aggG, 256, 64, Bhi1, Blo1, bg1, h2, 256);

  // Layer 3: RGCN (256 -> 64) + elu: fused MFMA transform (of-split x4) -> xr + root
  gemm_l3_fused_kernel<<<dim3(4, gridM64), BLK, 0, stream>>>(h2, Bhi2, Blo2, comp2, xr, rootb);
  rgcn2_agg_kernel<<<gridW, BLK, 0, stream>>>(xr, rootb, brg2, offs, csr_src, csr_et, h3);

  // Layer 4: GAT (64 -> 4x3, mean heads) + mean classes + tanh
  gat_lin2_kernel<<<gridW4, BLK, 0, stream>>>(h3, Wg2, atts2, attd2, hw2, as2, ad2);
  gat2_final_kernel<<<gridW4, BLK, 0, stream>>>(hw2, as2, ad2, bg2, offs, csr_src, out);
}

// Round 20
// 265.827 us; speedup vs baseline: 1.2283x; 1.0339x over previous
//
#include <hip/hip_runtime.h>
#include <cstdint>
#include <cstddef>

#define NN 30000
#define NE 480000

typedef __attribute__((ext_vector_type(8))) short short8v;
typedef __attribute__((ext_vector_type(4))) float f32x4;

__device__ __forceinline__ float leakyf(float x){ return x > 0.f ? x : 0.2f * x; }
__device__ __forceinline__ float eluf(float x){ return x > 0.f ? x : expm1f(x); }

__device__ __forceinline__ float bf2f(unsigned short u){
  return __uint_as_float(((unsigned)u) << 16);
}
__device__ __forceinline__ unsigned short f2bf(float f){
  unsigned x = __float_as_uint(f);
  unsigned r = (x + 0x7FFFu + ((x >> 16) & 1u)) >> 16;
  return (unsigned short)r;
}

struct F4 { float x, y, z, w; };

__device__ __forceinline__ F4 ld4(const float* p){
  float4 v = *(const float4*)p;
  return F4{v.x, v.y, v.z, v.w};
}

__device__ __forceinline__ float4 redeg16(float4 v){
  v.x += __shfl_xor(v.x, 16); v.y += __shfl_xor(v.y, 16);
  v.z += __shfl_xor(v.z, 16); v.w += __shfl_xor(v.w, 16);
  v.x += __shfl_xor(v.x, 32); v.y += __shfl_xor(v.y, 32);
  v.z += __shfl_xor(v.z, 32); v.w += __shfl_xor(v.w, 32);
  return v;
}

// ---------------- CSR build ----------------

__global__ void zero2_kernel(int* __restrict__ a, int* __restrict__ b, int n){
  int i = blockIdx.x * blockDim.x + threadIdx.x;
  if (i < n){ a[i] = 0; b[i] = 0; }
}

__global__ void count_kernel(const int* __restrict__ dst, int* __restrict__ deg, int E){
  int i = blockIdx.x * blockDim.x + threadIdx.x;
  if (i < E) atomicAdd(&deg[dst[i]], 1);
}

__global__ void scan1_kernel(const int* __restrict__ deg, int* __restrict__ offs,
                             int* __restrict__ bsum){
  __shared__ int sh[256];
  int blk = blockIdx.x, t = threadIdx.x, i = blk * 256 + t;
  int v = (i < NN) ? deg[i] : 0;
  sh[t] = v; __syncthreads();
  for (int o = 1; o < 256; o <<= 1){
    int tv = (t >= o) ? sh[t - o] : 0;
    __syncthreads();
    sh[t] += tv;
    __syncthreads();
  }
  if (i < NN) offs[i + 1] = sh[t];
  if (t == 255) bsum[blk] = sh[255];
}

__global__ void scan2_kernel(int* __restrict__ bsum, int nb){
  __shared__ int sh[256];
  int t = threadIdx.x;
  int v = (t < nb) ? bsum[t] : 0;
  sh[t] = v; __syncthreads();
  for (int o = 1; o < 256; o <<= 1){
    int tv = (t >= o) ? sh[t - o] : 0;
    __syncthreads();
    sh[t] += tv;
    __syncthreads();
  }
  if (t < nb) bsum[t] = sh[t];
}

__global__ void scan3_kernel(const int* __restrict__ bsum, int* __restrict__ offs){
  int i = blockIdx.x * 256 + threadIdx.x;
  if (i == 0) offs[0] = 0;
  if (i < NN){
    int blk = i >> 8;
    int add = blk ? bsum[blk - 1] : 0;
    offs[i + 1] += add;
  }
}

__global__ void scatter_kernel(const int* __restrict__ src, const int* __restrict__ dst,
                               const int* __restrict__ et, const int* __restrict__ offs,
                               int* __restrict__ cursor, int* __restrict__ csr_src,
                               int* __restrict__ csr_et, int E){
  int i = blockIdx.x * blockDim.x + threadIdx.x;
  if (i < E){
    int d = dst[i];
    int pos = offs[d] + atomicAdd(&cursor[d], 1);
    csr_src[pos] = src[i];
    csr_et[pos]  = et[i];
  }
}

// ---------------- weight prep ----------------

// L3 B-fragments straight from basis2/root2 (virtual Wcat cols: 0..255 basis, 256..319 root).
__global__ void packB2_kernel(const float* __restrict__ basis2, const float* __restrict__ root2,
                              unsigned short* __restrict__ Bhi, unsigned short* __restrict__ Blo){
  int idx = blockIdx.x * 256 + threadIdx.x;
  if (idx >= 10240) return;
  int lane = idx & 63;
  int rest = idx >> 6;
  int ks = rest & 7;
  int nf16 = rest >> 3;                       // 0..19
  int col = nf16 * 16 + (lane & 15);
  int kbase = ks * 32 + ((lane >> 4) << 3);
  size_t obase = (size_t)idx * 8;
  #pragma unroll
  for (int j = 0; j < 8; j++){
    int k = kbase + j;
    float v;
    if (col < 256){
      int b = col >> 6, c = col & 63;
      v = basis2[((size_t)b * 256 + k) * 64 + c];
    } else {
      v = root2[(size_t)k * 64 + (col - 256)];
    }
    unsigned short h = f2bf(v);
    float res = v - bf2f(h);
    Bhi[obase + j] = h;
    Blo[obase + j] = f2bf(res);
  }
}

// generic MFMA B-fragment pack (GAT1 Wg1), bf16 hi/lo split.
__global__ void packB_kernel(const float* __restrict__ W, int ldw, int ksteps, int total,
                             unsigned short* __restrict__ Bhi, unsigned short* __restrict__ Blo){
  int idx = blockIdx.x * 256 + threadIdx.x;
  if (idx >= total) return;
  int lane = idx & 63;
  int rest = idx >> 6;
  int ks = rest % ksteps;
  int nf16 = rest / ksteps;
  int col = nf16 * 16 + (lane & 15);
  int kbase = ks * 32 + ((lane >> 4) << 3);
  size_t obase = (size_t)idx * 8;
  #pragma unroll
  for (int j = 0; j < 8; j++){
    float v = W[(size_t)(kbase + j) * ldw + col];
    unsigned short h = f2bf(v);
    float res = v - bf2f(h);
    Bhi[obase + j] = h;
    Blo[obase + j] = f2bf(res);
  }
}

// wa_s[k*4+h] = sum_c Wg1[k, h*64+c] * atts1[h,c]  (and wa_d with attd1)
__global__ void wa_kernel(const float* __restrict__ Wg1, const float* __restrict__ atts1,
                          const float* __restrict__ attd1, float* __restrict__ wa_s,
                          float* __restrict__ wa_d){
  int t = threadIdx.x;
  int k = t >> 2, h = t & 3;
  float s = 0.f, d = 0.f;
  const float* wr = Wg1 + (size_t)k * 256 + h * 64;
  const float* pa = atts1 + h * 64;
  const float* pb = attd1 + h * 64;
  #pragma unroll 8
  for (int c = 0; c < 64; c++){ s += wr[c] * pa[c]; d += wr[c] * pb[c]; }
  wa_s[k * 4 + h] = s;
  wa_d[k * 4 + h] = d;
}

// ---------------- layer-1 basis-space aggregation (4 edge-groups x float2) ----------------

__global__ void agg1_kernel(const float* __restrict__ x, const float* __restrict__ comp,
                            const int* __restrict__ offs, const int* __restrict__ csr_src,
                            const int* __restrict__ csr_et, float* __restrict__ agg){
  int wid  = (blockIdx.x * blockDim.x + threadIdx.x) >> 6;
  int lane = threadIdx.x & 63;
  if (wid >= NN) return;
  int q = lane & 15, eg = lane >> 4;
  int c2 = q * 2;
  int n0 = offs[wid], n1 = offs[wid + 1];
  float a00 = 0.f, a01 = 0.f, a10 = 0.f, a11 = 0.f;
  float a20 = 0.f, a21 = 0.f, a30 = 0.f, a31 = 0.f;
  for (int k = n0 + eg; k < n1; k += 4){
    int s = csr_src[k], e = csr_et[k];
    float2 v = *(const float2*)(x + (size_t)s * 32 + c2);
    F4 cp = ld4(comp + (size_t)e * 4);
    a00 += cp.x * v.x; a01 += cp.x * v.y;
    a10 += cp.y * v.x; a11 += cp.y * v.y;
    a20 += cp.z * v.x; a21 += cp.z * v.y;
    a30 += cp.w * v.x; a31 += cp.w * v.y;
  }
  #pragma unroll
  for (int o = 16; o < 64; o <<= 1){
    a00 += __shfl_xor(a00, o); a01 += __shfl_xor(a01, o);
    a10 += __shfl_xor(a10, o); a11 += __shfl_xor(a11, o);
    a20 += __shfl_xor(a20, o); a21 += __shfl_xor(a21, o);
    a30 += __shfl_xor(a30, o); a31 += __shfl_xor(a31, o);
  }
  int dg = n1 - n0;
  float sc = 1.f / (float)(dg > 0 ? dg : 1);
  if (lane < 16){
    float* ar = agg + (size_t)wid * 128 + c2;
    *(float2*)(ar)      = make_float2(a00 * sc, a01 * sc);
    *(float2*)(ar + 32) = make_float2(a10 * sc, a11 * sc);
    *(float2*)(ar + 64) = make_float2(a20 * sc, a21 * sc);
    *(float2*)(ar + 96) = make_float2(a30 * sc, a31 * sc);
  }
}

// ---------------- (RPT*16)-row x 64-col fused GEMM (layer 1), logits fused ----------------

template<int RPT, bool ELU, bool LOGITS>
__global__ __launch_bounds__(256) void gemmT_kernel(
    const float* __restrict__ A1, int lda1, int K1,
    const float* __restrict__ W1, int ldw1,
    const float* __restrict__ A2, int lda2, int K2,
    const float* __restrict__ W2, int ldw2,
    const float* __restrict__ bias,
    float* __restrict__ Y, int ldy,
    int nrows,
    const float* __restrict__ wa_s, const float* __restrict__ wa_d,
    float* __restrict__ as_, float* __restrict__ ad_)
{
  __shared__ float At[32][RPT * 16 + 4];
  __shared__ float Wl[32][68];
  int t = threadIdx.x;
  int tc = t & 15, tr = t >> 4;
  int nbase = blockIdx.x * (RPT * 16);
  float acc[RPT][4];
  #pragma unroll
  for (int j = 0; j < RPT; j++)
    #pragma unroll
    for (int i = 0; i < 4; i++) acc[j][i] = 0.f;

  for (int seg = 0; seg < 2; seg++){
    const float* A = seg ? A2 : A1;
    const float* W = seg ? W2 : W1;
    int lda = seg ? lda2 : lda1;
    int ldw = seg ? ldw2 : ldw1;
    int K   = seg ? K2 : K1;
    if (A == nullptr || K <= 0) continue;
    for (int k0 = 0; k0 < K; k0 += 32){
      #pragma unroll
      for (int i = 0; i < 2; i++){
        int e = i * 256 + t;
        int kk = e >> 4, c4 = (e & 15) << 2;
        float4 v = make_float4(0.f, 0.f, 0.f, 0.f);
        if (k0 + kk < K) v = *(const float4*)(W + (size_t)(k0 + kk) * ldw + c4);
        *(float4*)&Wl[kk][c4] = v;
      }
      #pragma unroll
      for (int i = 0; i < RPT / 2; i++){
        int e = i * 256 + t;
        int r = e >> 3, c4 = (e & 7) << 2;
        int n = nbase + r;
        float4 v = make_float4(0.f, 0.f, 0.f, 0.f);
        if (n < nrows && k0 + c4 < K) v = *(const float4*)(A + (size_t)n * lda + k0 + c4);
        At[c4 + 0][r] = v.x;
        At[c4 + 1][r] = v.y;
        At[c4 + 2][r] = v.z;
        At[c4 + 3][r] = v.w;
      }
      __syncthreads();
      #pragma unroll 4
      for (int k = 0; k < 32; k++){
        float4 wv = *(const float4*)&Wl[k][tc * 4];
        const float* pw = (const float*)&wv;
        #pragma unroll
        for (int jj = 0; jj < RPT / 4; jj++){
          float4 av = *(const float4*)&At[k][tr * RPT + jj * 4];
          const float* pa = (const float*)&av;
          #pragma unroll
          for (int j = 0; j < 4; j++)
            #pragma unroll
            for (int i = 0; i < 4; i++)
              acc[jj * 4 + j][i] = fmaf(pa[j], pw[i], acc[jj * 4 + j][i]);
        }
      }
      __syncthreads();
    }
  }

  float b0 = bias[tc * 4 + 0], b1 = bias[tc * 4 + 1];
  float b2 = bias[tc * 4 + 2], b3 = bias[tc * 4 + 3];
  float4 ws0, ws1, ws2, ws3, wd0, wd1, wd2, wd3;
  if (LOGITS){
    ws0 = *(const float4*)(wa_s + (tc*4+0)*4); wd0 = *(const float4*)(wa_d + (tc*4+0)*4);
    ws1 = *(const float4*)(wa_s + (tc*4+1)*4); wd1 = *(const float4*)(wa_d + (tc*4+1)*4);
    ws2 = *(const float4*)(wa_s + (tc*4+2)*4); wd2 = *(const float4*)(wa_d + (tc*4+2)*4);
    ws3 = *(const float4*)(wa_s + (tc*4+3)*4); wd3 = *(const float4*)(wa_d + (tc*4+3)*4);
  }
  #pragma unroll
  for (int j = 0; j < RPT; j++){
    int n = nbase + tr * RPT + j;
    float y0 = acc[j][0] + b0, y1 = acc[j][1] + b1;
    float y2 = acc[j][2] + b2, y3 = acc[j][3] + b3;
    if (ELU){ y0 = eluf(y0); y1 = eluf(y1); y2 = eluf(y2); y3 = eluf(y3); }
    if (n < nrows)
      *(float4*)(Y + (size_t)n * ldy + tc * 4) = make_float4(y0, y1, y2, y3);
    if (LOGITS){
      float s0 = y0*ws0.x + y1*ws1.x + y2*ws2.x + y3*ws3.x;
      float s1 = y0*ws0.y + y1*ws1.y + y2*ws2.y + y3*ws3.y;
      float s2 = y0*ws0.z + y1*ws1.z + y2*ws2.z + y3*ws3.z;
      float s3 = y0*ws0.w + y1*ws1.w + y2*ws2.w + y3*ws3.w;
      float d0 = y0*wd0.x + y1*wd1.x + y2*wd2.x + y3*wd3.x;
      float d1 = y0*wd0.y + y1*wd1.y + y2*wd2.y + y3*wd3.y;
      float d2 = y0*wd0.z + y1*wd1.z + y2*wd2.z + y3*wd3.z;
      float d3 = y0*wd0.w + y1*wd1.w + y2*wd2.w + y3*wd3.w;
      #pragma unroll
      for (int o = 1; o < 16; o <<= 1){
        s0 += __shfl_xor(s0, o); s1 += __shfl_xor(s1, o);
        s2 += __shfl_xor(s2, o); s3 += __shfl_xor(s3, o);
        d0 += __shfl_xor(d0, o); d1 += __shfl_xor(d1, o);
        d2 += __shfl_xor(d2, o); d3 += __shfl_xor(d3, o);
      }
      if (tc == 0 && n < nrows){
        *(float4*)(as_ + n * 4) = make_float4(s0, s1, s2, s3);
        *(float4*)(ad_ + n * 4) = make_float4(d0, d1, d2, d3);
      }
    }
  }
}

// ---------------- bf16-split MFMA GEMM (GAT1 block-diag), 16-row waves ----------------
// grid (ncg, ceil(N/64)); wave = 16 rows x 64 cols; acc[4] f32x4.

template<int KSTEPS, bool ELU, bool BIAS>
__global__ __launch_bounds__(256) void gemm_mfma_kernel(
    const float* __restrict__ A, int lda, int acgoff,
    const unsigned short* __restrict__ Bhi, const unsigned short* __restrict__ Blo,
    const float* __restrict__ bias, float* __restrict__ Y, int ldy)
{
  int t = threadIdx.x;
  int lane = t & 63, wv = t >> 6;
  int cg = blockIdx.x;
  int mbase = blockIdx.y * 64 + wv * 16;
  int fr = lane & 15;
  int ksub = (lane >> 4) << 3;
  const float* Ab = A + (size_t)cg * acgoff;
  f32x4 acc[4];
  #pragma unroll
  for (int ni = 0; ni < 4; ni++)
    acc[ni] = (f32x4){0.f, 0.f, 0.f, 0.f};

  int ar = mbase + fr;
  bool arok = (ar < NN);
  #pragma unroll
  for (int ks = 0; ks < KSTEPS; ks++){
    float av[8];
    if (arok){
      float4 p0 = *(const float4*)(Ab + (size_t)ar * lda + ks * 32 + ksub);
      float4 p1 = *(const float4*)(Ab + (size_t)ar * lda + ks * 32 + ksub + 4);
      av[0] = p0.x; av[1] = p0.y; av[2] = p0.z; av[3] = p0.w;
      av[4] = p1.x; av[5] = p1.y; av[6] = p1.z; av[7] = p1.w;
    } else {
      #pragma unroll
      for (int j = 0; j < 8; j++) av[j] = 0.f;
    }
    short8v ahi, alo;
    #pragma unroll
    for (int j = 0; j < 8; j++){
      unsigned short h = f2bf(av[j]);
      float res = av[j] - bf2f(h);
      ahi[j] = (short)h;
      alo[j] = (short)f2bf(res);
    }
    #pragma unroll
    for (int ni = 0; ni < 4; ni++){
      size_t boff = ((((size_t)(cg * 4 + ni)) * KSTEPS + ks) * 64 + lane) * 8;
      short8v bh = *(const short8v*)(Bhi + boff);
      short8v bl = *(const short8v*)(Blo + boff);
      acc[ni] = __builtin_amdgcn_mfma_f32_16x16x32_bf16(ahi, bh, acc[ni], 0, 0, 0);
      acc[ni] = __builtin_amdgcn_mfma_f32_16x16x32_bf16(ahi, bl, acc[ni], 0, 0, 0);
      acc[ni] = __builtin_amdgcn_mfma_f32_16x16x32_bf16(alo, bh, acc[ni], 0, 0, 0);
    }
  }
  int crow = (lane >> 4) << 2;
  #pragma unroll
  for (int reg = 0; reg < 4; reg++){
    int r = mbase + crow + reg;
    if (r < NN){
      #pragma unroll
      for (int ni = 0; ni < 4; ni++){
        float y = acc[ni][reg];
        if (BIAS) y += bias[cg * 64 + ni * 16 + fr];
        if (ELU)  y = eluf(y);
        Y[(size_t)r * ldy + cg * 64 + ni * 16 + fr] = y;
      }
    }
  }
}

// ---------------- L3 fused MFMA GEMM, 4-way of-split (measured best) ----------------

__global__ __launch_bounds__(256) void gemm_l3_fused_kernel(
    const float* __restrict__ A,
    const unsigned short* __restrict__ Bhi, const unsigned short* __restrict__ Blo,
    const float* __restrict__ comp2,
    unsigned short* __restrict__ xr, float* __restrict__ rootb)
{
  int t = threadIdx.x;
  int lane = t & 63, wv = t >> 6;
  int of = blockIdx.x;
  int mbase = blockIdx.y * 64 + wv * 16;
  int fr = lane & 15;
  int ksub = (lane >> 4) << 3;
  f32x4 acc[5];
  #pragma unroll
  for (int b = 0; b < 5; b++) acc[b] = (f32x4){0.f, 0.f, 0.f, 0.f};

  int ar = mbase + fr;
  bool arok = (ar < NN);
  for (int ks = 0; ks < 8; ks++){
    float av[8];
    if (arok){
      float4 p0 = *(const float4*)(A + (size_t)ar * 256 + ks * 32 + ksub);
      float4 p1 = *(const float4*)(A + (size_t)ar * 256 + ks * 32 + ksub + 4);
      av[0] = p0.x; av[1] = p0.y; av[2] = p0.z; av[3] = p0.w;
      av[4] = p1.x; av[5] = p1.y; av[6] = p1.z; av[7] = p1.w;
    } else {
      #pragma unroll
      for (int j = 0; j < 8; j++) av[j] = 0.f;
    }
    short8v ahi, alo;
    #pragma unroll
    for (int j = 0; j < 8; j++){
      unsigned short h = f2bf(av[j]);
      float res = av[j] - bf2f(h);
      ahi[j] = (short)h;
      alo[j] = (short)f2bf(res);
    }
    #pragma unroll
    for (int b = 0; b < 5; b++){
      int nig = b * 4 + of;                 // b<4: basis, b=4: root
      size_t boff = (((size_t)nig * 8 + ks) * 64 + lane) * 8;
      short8v bh = *(const short8v*)(Bhi + boff);
      short8v bl = *(const short8v*)(Blo + boff);
      acc[b] = __builtin_amdgcn_mfma_f32_16x16x32_bf16(ahi, bh, acc[b], 0, 0, 0);
      acc[b] = __builtin_amdgcn_mfma_f32_16x16x32_bf16(ahi, bl, acc[b], 0, 0, 0);
      acc[b] = __builtin_amdgcn_mfma_f32_16x16x32_bf16(alo, bh, acc[b], 0, 0, 0);
    }
  }

  float cp[32];
  #pragma unroll
  for (int i = 0; i < 32; i++) cp[i] = comp2[i];
  int crow = (lane >> 4) << 2;
  int col = of * 16 + fr;
  #pragma unroll
  for (int reg = 0; reg < 4; reg++){
    int r = mbase + crow + reg;
    if (r >= NN) continue;
    float b0 = acc[0][reg], b1 = acc[1][reg], b2 = acc[2][reg], b3 = acc[3][reg];
    rootb[(size_t)r * 64 + col] = acc[4][reg];
    #pragma unroll
    for (int rr = 0; rr < 8; rr++){
      float m = cp[rr*4+0]*b0 + cp[rr*4+1]*b1 + cp[rr*4+2]*b2 + cp[rr*4+3]*b3;
      xr[((size_t)r * 8 + rr) * 64 + col] = f2bf(m);
    }
  }
}

// ---------------- GAT1 aggregate: 4 edge-groups x 16 ch-lanes, 4 heads per lane ----------------

__global__ void gat1_agg_kernel(const float* __restrict__ h1, const float* __restrict__ as_,
                                const float* __restrict__ ad_, const int* __restrict__ offs,
                                const int* __restrict__ csr_src, float* __restrict__ aggG){
  int wid  = (blockIdx.x * blockDim.x + threadIdx.x) >> 6;
  int lane = threadIdx.x & 63;
  if (wid >= NN) return;
  int n0 = offs[wid], n1 = offs[wid + 1];
  int h = lane & 3;
  float adn_s = ad_[wid * 4 + h];
  float m = leakyf(as_[wid * 4 + h] + adn_s);
  for (int k = n0 + (lane >> 2); k < n1; k += 16){
    int s = csr_src[k];
    m = fmaxf(m, leakyf(as_[s * 4 + h] + adn_s));
  }
  #pragma unroll
  for (int o = 4; o < 64; o <<= 1) m = fmaxf(m, __shfl_xor(m, o));
  float m0 = __shfl(m, 0), m1 = __shfl(m, 1), m2 = __shfl(m, 2), m3 = __shfl(m, 3);
  int q = lane & 15, eg = lane >> 4;
  F4 adn = ld4(ad_ + (size_t)wid * 4);
  float den0 = 0.f, den1 = 0.f, den2 = 0.f, den3 = 0.f;
  float4 ac0 = make_float4(0.f,0.f,0.f,0.f), ac1 = ac0, ac2 = ac0, ac3 = ac0;
  for (int k = n0 + eg; k < n1; k += 4){
    int s = csr_src[k];
    F4 a = ld4(as_ + (size_t)s * 4);
    float p0 = expf(leakyf(a.x + adn.x) - m0);
    float p1 = expf(leakyf(a.y + adn.y) - m1);
    float p2 = expf(leakyf(a.z + adn.z) - m2);
    float p3 = expf(leakyf(a.w + adn.w) - m3);
    den0 += p0; den1 += p1; den2 += p2; den3 += p3;
    float4 v = *(const float4*)(h1 + (size_t)s * 64 + q * 4);
    ac0.x += p0*v.x; ac0.y += p0*v.y; ac0.z += p0*v.z; ac0.w += p0*v.w;
    ac1.x += p1*v.x; ac1.y += p1*v.y; ac1.z += p1*v.z; ac1.w += p1*v.w;
    ac2.x += p2*v.x; ac2.y += p2*v.y; ac2.z += p2*v.z; ac2.w += p2*v.w;
    ac3.x += p3*v.x; ac3.y += p3*v.y; ac3.z += p3*v.z; ac3.w += p3*v.w;
  }
  #pragma unroll
  for (int o = 16; o < 64; o <<= 1){
    den0 += __shfl_xor(den0, o); den1 += __shfl_xor(den1, o);
    den2 += __shfl_xor(den2, o); den3 += __shfl_xor(den3, o);
  }
  ac0 = redeg16(ac0); ac1 = redeg16(ac1); ac2 = redeg16(ac2); ac3 = redeg16(ac3);
  F4 asn = ld4(as_ + (size_t)wid * 4);
  float ps0 = expf(leakyf(asn.x + adn.x) - m0);
  float ps1 = expf(leakyf(asn.y + adn.y) - m1);
  float ps2 = expf(leakyf(asn.z + adn.z) - m2);
  float ps3 = expf(leakyf(asn.w + adn.w) - m3);
  if (lane < 16){
    float4 v = *(const float4*)(h1 + (size_t)wid * 64 + q * 4);
    float i0 = 1.f / (den0 + ps0), i1 = 1.f / (den1 + ps1);
    float i2 = 1.f / (den2 + ps2), i3 = 1.f / (den3 + ps3);
    float* ag = aggG + (size_t)wid * 256 + q * 4;
    *(float4*)(ag)       = make_float4((ac0.x+ps0*v.x)*i0, (ac0.y+ps0*v.y)*i0, (ac0.z+ps0*v.z)*i0, (ac0.w+ps0*v.w)*i0);
    *(float4*)(ag + 64)  = make_float4((ac1.x+ps1*v.x)*i1, (ac1.y+ps1*v.y)*i1, (ac1.z+ps1*v.z)*i1, (ac1.w+ps1*v.w)*i1);
    *(float4*)(ag + 128) = make_float4((ac2.x+ps2*v.x)*i2, (ac2.y+ps2*v.y)*i2, (ac2.z+ps2*v.z)*i2, (ac2.w+ps2*v.w)*i2);
    *(float4*)(ag + 192) = make_float4((ac3.x+ps3*v.x)*i3, (ac3.y+ps3*v.y)*i3, (ac3.z+ps3*v.z)*i3, (ac3.w+ps3*v.w)*i3);
  }
}

// ---------------- layer-3 aggregate: 8 edge-groups x 8 ch-lanes (ushort8 gathers) ----------

__global__ void rgcn2_agg_kernel(const unsigned short* __restrict__ xr,
                                 const float* __restrict__ rootb,
                                 const float* __restrict__ bias, const int* __restrict__ offs,
                                 const int* __restrict__ csr_src, const int* __restrict__ csr_et,
                                 float* __restrict__ h3){
  int wid  = (blockIdx.x * blockDim.x + threadIdx.x) >> 6;
  int lane = threadIdx.x & 63;
  if (wid >= NN) return;
  int q = lane & 7, eg = lane >> 3;
  int n0 = offs[wid], n1 = offs[wid + 1];
  float a[8];
  #pragma unroll
  for (int j = 0; j < 8; j++) a[j] = 0.f;
  for (int k = n0 + eg; k < n1; k += 8){
    int s = csr_src[k], e = csr_et[k];
    short8v u = *(const short8v*)(xr + ((size_t)s * 8 + e) * 64 + q * 8);
    #pragma unroll
    for (int j = 0; j < 8; j++) a[j] += bf2f((unsigned short)u[j]);
  }
  #pragma unroll
  for (int o = 8; o < 64; o <<= 1){
    #pragma unroll
    for (int j = 0; j < 8; j++) a[j] += __shfl_xor(a[j], o);
  }
  int dg = n1 - n0;
  float sc = 1.f / (float)(dg > 0 ? dg : 1);
  if (lane < 8){
    const float* rb = rootb + (size_t)wid * 64 + q * 8;
    float4 r0 = *(const float4*)(rb);
    float4 r1 = *(const float4*)(rb + 4);
    float4 b0 = *(const float4*)(bias + q * 8);
    float4 b1 = *(const float4*)(bias + q * 8 + 4);
    float* hp = h3 + (size_t)wid * 64 + q * 8;
    *(float4*)(hp)     = make_float4(eluf(a[0]*sc + r0.x + b0.x), eluf(a[1]*sc + r0.y + b0.y),
                                     eluf(a[2]*sc + r0.z + b0.z), eluf(a[3]*sc + r0.w + b0.w));
    *(float4*)(hp + 4) = make_float4(eluf(a[4]*sc + r1.x + b1.x), eluf(a[5]*sc + r1.y + b1.y),
                                     eluf(a[6]*sc + r1.z + b1.z), eluf(a[7]*sc + r1.w + b1.w));
  }
}

// ---------------- GAT2: linear (4 nodes/wave, 16 lanes/node) ----------------

__global__ void gat_lin2_kernel(const float* __restrict__ h, const float* __restrict__ W,
                                const float* __restrict__ atts, const float* __restrict__ attd,
                                float* __restrict__ hw, float* __restrict__ as_, float* __restrict__ ad_){
  __shared__ float Wl[64][13];
  __shared__ float sa[12], sd[12];
  int t = threadIdx.x;
  for (int i = t; i < 768; i += 256) Wl[i / 12][i % 12] = W[i];
  if (t < 12){ sa[t] = atts[t]; sd[t] = attd[t]; }
  __syncthreads();
  int idx = blockIdx.x * 256 + t;
  int n = idx >> 4, c = idx & 15;
  if (n >= NN) return;
  float acc = 0.f;
  if (c < 12){
    const float* hr = h + (size_t)n * 64;
    #pragma unroll 8
    for (int i = 0; i < 64; i++) acc += hr[i] * Wl[i][c];
    hw[(size_t)n * 12 + c] = acc;
  }
  float ts = (c < 12) ? acc * sa[c] : 0.f;
  float td = (c < 12) ? acc * sd[c] : 0.f;
  int lane = t & 63;
  int base = lane & 48;                       // 16-lane group base
  int b = base + ((c < 4) ? c * 3 : 0);
  float s0 = __shfl(ts, b) + __shfl(ts, b + 1) + __shfl(ts, b + 2);
  float d0 = __shfl(td, b) + __shfl(td, b + 1) + __shfl(td, b + 2);
  if (c < 4){ as_[n * 4 + c] = s0; ad_[n * 4 + c] = d0; }
}

// ---------------- GAT2 final: 4 nodes/wave, 16 edge-lanes/node ----------------

__global__ void gat2_final_kernel(const float* __restrict__ hw, const float* __restrict__ as_,
                                  const float* __restrict__ ad_, const float* __restrict__ bg2,
                                  const int* __restrict__ offs, const int* __restrict__ csr_src,
                                  float* __restrict__ out){
  int gwid = (blockIdx.x * blockDim.x + threadIdx.x) >> 6;  // wave id
  int lane = threadIdx.x & 63;
  int g = lane >> 4, e = lane & 15;
  int node = gwid * 4 + g;
  if (node >= NN) return;
  int n0 = offs[node], n1 = offs[node + 1];
  F4 adn = ld4(ad_ + (size_t)node * 4);
  F4 asn = ld4(as_ + (size_t)node * 4);
  F4 es{leakyf(asn.x + adn.x), leakyf(asn.y + adn.y), leakyf(asn.z + adn.z), leakyf(asn.w + adn.w)};
  F4 m = es;
  for (int k = n0 + e; k < n1; k += 16){
    int s = csr_src[k];
    F4 a = ld4(as_ + (size_t)s * 4);
    m.x = fmaxf(m.x, leakyf(a.x + adn.x));
    m.y = fmaxf(m.y, leakyf(a.y + adn.y));
    m.z = fmaxf(m.z, leakyf(a.z + adn.z));
    m.w = fmaxf(m.w, leakyf(a.w + adn.w));
  }
  #pragma unroll
  for (int o = 1; o < 16; o <<= 1){
    m.x = fmaxf(m.x, __shfl_xor(m.x, o));
    m.y = fmaxf(m.y, __shfl_xor(m.y, o));
    m.z = fmaxf(m.z, __shfl_xor(m.z, o));
    m.w = fmaxf(m.w, __shfl_xor(m.w, o));
  }
  F4 ps{expf(es.x - m.x), expf(es.y - m.y), expf(es.z - m.z), expf(es.w - m.w)};
  float acc[12];
  #pragma unroll
  for (int j = 0; j < 12; j++) acc[j] = 0.f;
  F4 denp{0.f, 0.f, 0.f, 0.f};
  for (int k = n0 + e; k < n1; k += 16){
    int s = csr_src[k];
    F4 a = ld4(as_ + (size_t)s * 4);
    F4 p{expf(leakyf(a.x + adn.x) - m.x), expf(leakyf(a.y + adn.y) - m.y),
         expf(leakyf(a.z + adn.z) - m.z), expf(leakyf(a.w + adn.w) - m.w)};
    denp.x += p.x; denp.y += p.y; denp.z += p.z; denp.w += p.w;
    const float* hb = hw + (size_t)s * 12;
    F4 h0 = ld4(hb), h1 = ld4(hb + 4), h2 = ld4(hb + 8);
    acc[0] += p.x * h0.x; acc[1]  += p.x * h0.y; acc[2]  += p.x * h0.z;
    acc[3] += p.y * h0.w; acc[4]  += p.y * h1.x; acc[5]  += p.y * h1.y;
    acc[6] += p.z * h1.z; acc[7]  += p.z * h1.w; acc[8]  += p.z * h2.x;
    acc[9] += p.w * h2.y; acc[10] += p.w * h2.z; acc[11] += p.w * h2.w;
  }
  #pragma unroll
  for (int o = 1; o < 16; o <<= 1){
    denp.x += __shfl_xor(denp.x, o);
    denp.y += __shfl_xor(denp.y, o);
    denp.z += __shfl_xor(denp.z, o);
    denp.w += __shfl_xor(denp.w, o);
    #pragma unroll
    for (int j = 0; j < 12; j++) acc[j] += __shfl_xor(acc[j], o);
  }
  if (e == 0){
    const float* hn = hw + (size_t)node * 12;
    float dn[4]  = {denp.x + ps.x, denp.y + ps.y, denp.z + ps.z, denp.w + ps.w};
    float psv[4] = {ps.x, ps.y, ps.z, ps.w};
    float tot = 0.f;
    #pragma unroll
    for (int h_ = 0; h_ < 4; h_++){
      #pragma unroll
      for (int c = 0; c < 3; c++){
        float num = acc[h_ * 3 + c] + psv[h_] * hn[h_ * 3 + c];
        tot += num / dn[h_];
      }
    }
    tot = tot / 12.f + (bg2[0] + bg2[1] + bg2[2]) / 3.f;
    out[node] = tanhf(tot);
  }
}

// ---------------- launch ----------------

extern "C" void kernel_launch(void* const* d_in, const int* in_sizes, int n_in,
                              void* d_out, int out_size, void* d_ws, size_t ws_size,
                              hipStream_t stream){
  const float* x      = (const float*)d_in[0];
  const int*   ei     = (const int*)d_in[1];
  const int*   et     = (const int*)d_in[2];
  const float* basis1 = (const float*)d_in[3];
  const float* comp1  = (const float*)d_in[4];
  const float* root1  = (const float*)d_in[5];
  const float* brg1   = (const float*)d_in[6];
  const float* Wg1    = (const float*)d_in[7];
  const float* atts1  = (const float*)d_in[8];
  const float* attd1  = (const float*)d_in[9];
  const float* bg1    = (const float*)d_in[10];
  const float* basis2 = (const float*)d_in[11];
  const float* comp2  = (const float*)d_in[12];
  const float* root2  = (const float*)d_in[13];
  const float* brg2   = (const float*)d_in[14];
  const float* Wg2    = (const float*)d_in[15];
  const float* atts2  = (const float*)d_in[16];
  const float* attd2  = (const float*)d_in[17];
  const float* bg2    = (const float*)d_in[18];
  float* out = (float*)d_out;

  const int* src = ei;
  const int* dst = ei + NE;

  char* ws = (char*)d_ws;
  size_t off = 0;
  auto alloc = [&](size_t bytes) -> void* {
    void* p = ws + off;
    off = (off + bytes + 255) & ~(size_t)255;
    return p;
  };
  // persistent
  int*   deg     = (int*)alloc((size_t)NN * 4);
  int*   cursor  = (int*)alloc((size_t)NN * 4);
  int*   offs    = (int*)alloc((size_t)(NN + 1) * 4);
  int*   bsum    = (int*)alloc((size_t)256 * 4);
  int*   csr_src = (int*)alloc((size_t)NE * 4);
  int*   csr_et  = (int*)alloc((size_t)NE * 4);
  unsigned short* Bhi2 = (unsigned short*)alloc((size_t)81920 * 2);  // L3: 20*8*64*8
  unsigned short* Blo2 = (unsigned short*)alloc((size_t)81920 * 2);
  unsigned short* Bhi1 = (unsigned short*)alloc((size_t)16384 * 2);  // GAT1: 16*2*64*8
  unsigned short* Blo1 = (unsigned short*)alloc((size_t)16384 * 2);
  float* wa_s    = (float*)alloc((size_t)256 * 4);
  float* wa_d    = (float*)alloc((size_t)256 * 4);
  float* h1      = (float*)alloc((size_t)NN * 64 * 4);
  float* h2      = (float*)alloc((size_t)NN * 256 * 4);
  float* h3      = (float*)alloc((size_t)NN * 64 * 4);
  float* hw2     = (float*)alloc((size_t)NN * 12 * 4);
  float* as1     = (float*)alloc((size_t)NN * 4 * 4);
  float* ad1     = (float*)alloc((size_t)NN * 4 * 4);
  float* as2     = (float*)alloc((size_t)NN * 4 * 4);
  float* ad2     = (float*)alloc((size_t)NN * 4 * 4);
  // scratch union S (NN*384 floats):
  //   agg1[NN*128] -> aggG[NN*256] -> { xr bf16 [NN*512] (= NN*256 floats), rootb [NN*64] }
  float* S       = (float*)alloc((size_t)NN * 384 * 4);
  float* agg1    = S;
  float* aggG    = S;
  unsigned short* xr = (unsigned short*)S;          // NN*512 ushorts = NN*256 floats
  float* rootb   = S + (size_t)NN * 256;            // NN*64 floats
  (void)ws_size; (void)n_in; (void)in_sizes; (void)out_size;

  const int BLK = 256;
  int gridN   = (NN + BLK - 1) / BLK;
  int gridE   = (NE + BLK - 1) / BLK;
  int gridW   = (NN + 3) / 4;       // 1 node/wave kernels
  int gridW4  = (NN + 15) / 16;     // 4 nodes/wave kernels
  int gridM64 = (NN + 63) / 64;     // 469

  // CSR build + weight prep
  zero2_kernel<<<gridN, BLK, 0, stream>>>(deg, cursor, NN);
  count_kernel<<<gridE, BLK, 0, stream>>>(dst, deg, NE);
  packB2_kernel<<<(10240 + 255) / 256, BLK, 0, stream>>>(basis2, root2, Bhi2, Blo2);
  packB_kernel<<<(2048 + 255) / 256, BLK, 0, stream>>>(Wg1, 256, 2, 2048, Bhi1, Blo1);
  wa_kernel<<<1, BLK, 0, stream>>>(Wg1, atts1, attd1, wa_s, wa_d);
  scan1_kernel<<<gridN, BLK, 0, stream>>>(deg, offs, bsum);
  scan2_kernel<<<1, BLK, 0, stream>>>(bsum, gridN);
  scan3_kernel<<<gridN, BLK, 0, stream>>>(bsum, offs);
  scatter_kernel<<<gridE, BLK, 0, stream>>>(src, dst, et, offs, cursor, csr_src, csr_et, NE);

  // Layer 1: RGCN (32 -> 64) + elu, GAT1 logits fused into epilogue
  agg1_kernel<<<gridW, BLK, 0, stream>>>(x, comp1, offs, csr_src, csr_et, agg1);
  gemmT_kernel<4, true, true><<<gridM64, BLK, 0, stream>>>(
      agg1, 128, 128, basis1, 64,
      x, 32, 32, root1, 64,
      brg1, h1, 64, NN, wa_s, wa_d, as1, ad1);

  // Layer 2: GAT (64 -> 256 concat) + elu: aggregate h1 -> MFMA block-diag GEMM (16-row waves)
  gat1_agg_kernel<<<gridW, BLK, 0, stream>>>(h1, as1, ad1, offs, csr_src, aggG);
  gemm_mfma_kernel<2, true, true><<<dim3(4, gridM64), BLK, 0, stream>>>(
      aggG, 256, 64, Bhi1, Blo1, bg1, h2, 256);

  // Layer 3: RGCN (256 -> 64) + elu: fused MFMA transform (of-split x4) -> xr + root
  gemm_l3_fused_kernel<<<dim3(4, gridM64), BLK, 0, stream>>>(h2, Bhi2, Blo2, comp2, xr, rootb);
  rgcn2_agg_kernel<<<gridW, BLK, 0, stream>>>(xr, rootb, brg2, offs, csr_src, csr_et, h3);

  // Layer 4: GAT (64 -> 4x3, mean heads) + mean classes + tanh
  gat_lin2_kernel<<<gridW4, BLK, 0, stream>>>(h3, Wg2, atts2, attd2, hw2, as2, ad2);
  gat2_final_kernel<<<gridW4, BLK, 0, stream>>>(hw2, as2, ad2, bg2, offs, csr_src, out);
}